// Round 12
// baseline (547.468 us; speedup 1.0000x reference)
//
#include <hip/hip_runtime.h>
#include <hip/hip_bf16.h>

// PhysicsGraphFusion: B=1024, N=7, D=1024
// Outputs (flat): fused (B*D), updated (B*N*D), imp (B*N), attn (B*N*N), phys (1), align (1)

typedef __attribute__((ext_vector_type(8))) short bf16x8;
typedef __attribute__((ext_vector_type(4))) float f32x4;

__constant__ float c_adj[49] = {
    1,1,0,0,1,1,1,
    1,1,1,1,1,1,1,
    0,1,1,0,1,0,1,
    0,1,0,1,1,1,1,
    1,1,1,1,1,1,1,
    1,1,0,1,1,1,1,
    1,1,1,1,1,1,1};

// gelu via Abramowitz-Stegun 7.1.26 erf (|err| < 1.5e-7, ~12 VALU ops).
__device__ __forceinline__ float gelu_f(float x) {
    float z = fabsf(x) * 0.70710678118654752f;
    float t = 1.0f / (1.0f + 0.3275911f * z);
    float poly = ((((1.061405429f * t - 1.453152027f) * t + 1.421413741f) * t
                  - 0.284496736f) * t + 0.254829592f) * t;
    float e = __expf(-z * z);
    float erf_abs = 1.0f - poly * e;
    float erf = copysignf(erf_abs, x);
    return 0.5f * x * (1.0f + erf);
}
__device__ __forceinline__ float b2f(unsigned short u) {
    unsigned int x = ((unsigned int)u) << 16;
    union { unsigned int i; float f; } c; c.i = x; return c.f;
}
__device__ __forceinline__ unsigned short f2b(float f) {
    __hip_bfloat16 h = __float2bfloat16(f);
    union { __hip_bfloat16 b; unsigned short u; } c; c.b = h; return c.u;
}

__device__ __forceinline__ void gload_lds16(const void* g, void* l) {
    __builtin_amdgcn_global_load_lds(
        (const __attribute__((address_space(1))) unsigned int*)g,
        (__attribute__((address_space(3))) unsigned int*)l, 16, 0, 0);
}

// row mapping: 0: r->r ; 1: r->r*7+6 (ctx rows) ; 2: r->r-r%7+6 (ctx broadcast)
__device__ __forceinline__ int maprow(int r, int mode) {
    if (mode == 1) return r * 7 + 6;
    if (mode == 2) return r - r % 7 + 6;
    return r;
}

// ---------------------------------------------------------------------------
// 128x128-tile double-buffered 4-wave bf16 MFMA GEMM (16x16x32 frags).
// PROVEN: R3/R7/R9/R11 measured 118.5-122.3 us on QKV shape, 0 bank
// conflicts, VGPR 76 -> ~31% occupancy. (R10 lesson: dual epilogues cost an
// occupancy step; keep single-path.)
// ---------------------------------------------------------------------------
__global__ __launch_bounds__(256) void gemm128db(
    const unsigned short* __restrict__ A1, int a1Mode,
    const unsigned short* __restrict__ A2, int a2Mode,
    const unsigned short* __restrict__ WT, int ldw,
    const float* __restrict__ bias,
    const float* __restrict__ resid,
    float* __restrict__ Cf,
    unsigned short* __restrict__ Cb, size_t segStride,
    int K, int act)
{
    __shared__ short As[2][128 * 32];
    __shared__ short Bs[2][128 * 32];
    const int tid = threadIdx.x;
    const int lane = tid & 63;
    const int w = tid >> 6;
    const int wr = (w >> 1) * 64;
    const int wc = (w & 1) * 64;

    int lin = blockIdx.y * gridDim.x + blockIdx.x;
    const int nwg = gridDim.x * gridDim.y;
    const int cpx = nwg >> 3;
    lin = (lin & 7) * cpx + (lin >> 3);
    const int row0 = (lin / gridDim.x) * 128;
    const int col0 = (lin % gridDim.x) * 128;

    const int fr = lane & 15;
    const int fko = (((lane >> 4) ^ ((fr >> 1) & 3)) << 3);

    const int NTt = K >> 5;

    auto stage = [&](int ktn) {
        int k0n = ktn * 32;
        const unsigned short* srcA; int mode; int kbase;
        if (k0n < 1024) { srcA = A1; mode = a1Mode; kbase = k0n; }
        else            { srcA = A2; mode = a2Mode; kbase = k0n - 1024; }
        short* Adst = &As[ktn & 1][0];
        short* Bdst = &Bs[ktn & 1][0];
        #pragma unroll
        for (int rnd = 0; rnd < 2; ++rnd) {
            int c = rnd * 256 + tid;
            int m = c >> 2, ch = c & 3;
            int kc = (ch ^ ((m >> 1) & 3)) * 8;
            int rr = maprow(row0 + m, mode);
            gload_lds16(srcA + (size_t)rr * 1024 + kbase + kc, Adst + c * 8);
        }
        #pragma unroll
        for (int rnd = 0; rnd < 2; ++rnd) {
            int c = rnd * 256 + tid;
            int n = c >> 2, ch = c & 3;
            int kc = (ch ^ ((n >> 1) & 3)) * 8;
            gload_lds16(WT + (size_t)(col0 + n) * ldw + k0n + kc, Bdst + c * 8);
        }
    };

    f32x4 acc[4][4] = {};

    stage(0);
    asm volatile("s_waitcnt vmcnt(0)" ::: "memory");
    asm volatile("s_barrier" ::: "memory");

    for (int kt = 0; kt < NTt; ++kt) {
        const short* Ab = &As[kt & 1][0];
        const short* Bb = &Bs[kt & 1][0];

        if (kt + 1 < NTt) stage(kt + 1);

        bf16x8 af[4], bfv[4];
        #pragma unroll
        for (int i = 0; i < 4; ++i)
            af[i] = *(const bf16x8*)(Ab + (wr + i * 16 + fr) * 32 + fko);
        #pragma unroll
        for (int j = 0; j < 4; ++j)
            bfv[j] = *(const bf16x8*)(Bb + (wc + j * 16 + fr) * 32 + fko);

        __builtin_amdgcn_s_setprio(1);
        #pragma unroll
        for (int i = 0; i < 4; ++i)
            #pragma unroll
            for (int j = 0; j < 4; ++j)
                acc[i][j] = __builtin_amdgcn_mfma_f32_16x16x32_bf16(
                    af[i], bfv[j], acc[i][j], 0, 0, 0);
        __builtin_amdgcn_s_setprio(0);

        asm volatile("s_waitcnt vmcnt(0)" ::: "memory");
        asm volatile("s_barrier" ::: "memory");
    }

    const int qrow = (lane >> 4) * 4;
    const int qcol = lane & 15;
    #pragma unroll
    for (int i = 0; i < 4; ++i) {
        int rbase = row0 + wr + i * 16 + qrow;
        #pragma unroll
        for (int j = 0; j < 4; ++j) {
            int c = col0 + wc + j * 16 + qcol;
            float bv = bias ? bias[c] : 0.0f;
            int seg = c >> 10, c0 = c & 1023;
            #pragma unroll
            for (int reg = 0; reg < 4; ++reg) {
                int r = rbase + reg;
                float vv = acc[i][j][reg] + bv;
                if (act) vv = gelu_f(vv);
                if (resid) vv += resid[(size_t)r * 1024 + c];
                if (Cf) Cf[(size_t)r * 1024 + c] = vv;
                if (Cb) Cb[(size_t)seg * segStride + (size_t)r * 1024 + c0] = f2b(vv);
            }
        }
    }
}

// ---------------------------------------------------------------------------
// 128x128-tile, 8-wave (512-thread) bf16 MFMA GEMM, 3-slot ring, counted
// vmcnt. PROVEN in R4. Used for the MLP GEMMs (448-block grids).
// w2 != nullptr: fused row-dot epilogue il[row] += sum_c gelu(acc + bias
// [+ resid[(r/7)*1024+c] ctx-broadcast]) * w2[c]. resid-broadcast is
// EPILOGUE-ONLY (no live range across the K-loop; R10 VGPR lesson).
// ---------------------------------------------------------------------------
__global__ __launch_bounds__(512, 4) void gemm128x8w(
    const unsigned short* __restrict__ A1, int a1Mode,
    const unsigned short* __restrict__ A2, int a2Mode,
    const unsigned short* __restrict__ WT, int ldw,
    const float* __restrict__ bias,
    const float* __restrict__ resid,
    float* __restrict__ Cf,
    unsigned short* __restrict__ Cb, size_t segStride,
    int K, int act,
    const float* __restrict__ w2, float* __restrict__ ildst)
{
    __shared__ short As[3][128 * 32];
    __shared__ short Bs[3][128 * 32];
    const int tid = threadIdx.x;
    const int lane = tid & 63;
    const int w = tid >> 6;            // 8 waves
    const int wr = (w >> 2) * 64;      // 0,64
    const int wc = (w & 3) * 32;       // 0,32,64,96

    int lin = blockIdx.y * gridDim.x + blockIdx.x;
    const int nwg = gridDim.x * gridDim.y;
    const int cpx = nwg >> 3;
    lin = (lin & 7) * cpx + (lin >> 3);
    const int row0 = (lin / gridDim.x) * 128;
    const int col0 = (lin % gridDim.x) * 128;

    const int fr = lane & 15;
    const int fko = (((lane >> 4) ^ ((fr >> 1) & 3)) << 3);

    const int sm_ = tid >> 2, sch = tid & 3;
    const int skc = (sch ^ ((sm_ >> 1) & 3)) * 8;
    const int ldsoff = tid * 8;

    const int NTt = K >> 5;

    auto stage = [&](int ktn) {
        int k0n = ktn * 32;
        const unsigned short* srcA; int mode; int kbase;
        if (k0n < 1024) { srcA = A1; mode = a1Mode; kbase = k0n; }
        else            { srcA = A2; mode = a2Mode; kbase = k0n - 1024; }
        int slot = ktn % 3;
        int rr = maprow(row0 + sm_, mode);
        gload_lds16(srcA + (size_t)rr * 1024 + kbase + skc, &As[slot][ldsoff]);
        gload_lds16(WT + (size_t)(col0 + sm_) * ldw + k0n + skc, &Bs[slot][ldsoff]);
    };

    f32x4 acc[4][2] = {};

    stage(0);
    if (NTt > 1) stage(1);
    asm volatile("s_waitcnt vmcnt(2)" ::: "memory");
    asm volatile("s_barrier" ::: "memory");

    for (int kt = 0; kt < NTt; ++kt) {
        const short* Ab = &As[kt % 3][0];
        const short* Bb = &Bs[kt % 3][0];

        if (kt + 2 < NTt) stage(kt + 2);

        bf16x8 af[4], bfv[2];
        #pragma unroll
        for (int i = 0; i < 4; ++i)
            af[i] = *(const bf16x8*)(Ab + (wr + i * 16 + fr) * 32 + fko);
        #pragma unroll
        for (int j = 0; j < 2; ++j)
            bfv[j] = *(const bf16x8*)(Bb + (wc + j * 16 + fr) * 32 + fko);

        __builtin_amdgcn_s_setprio(1);
        #pragma unroll
        for (int i = 0; i < 4; ++i)
            #pragma unroll
            for (int j = 0; j < 2; ++j)
                acc[i][j] = __builtin_amdgcn_mfma_f32_16x16x32_bf16(
                    af[i], bfv[j], acc[i][j], 0, 0, 0);
        __builtin_amdgcn_s_setprio(0);

        if (kt < NTt - 2) asm volatile("s_waitcnt vmcnt(2)" ::: "memory");
        else              asm volatile("s_waitcnt vmcnt(0)" ::: "memory");
        asm volatile("s_barrier" ::: "memory");
    }

    const int qrow = (lane >> 4) * 4;
    const int qcol = lane & 15;

    if (w2) {
        float* rowacc = (float*)&As[0][0];   // LDS reuse; all reads sealed
        if (tid < 128) rowacc[tid] = 0.f;
        __syncthreads();
        int c0 = col0 + wc + qcol;
        int c1 = col0 + wc + 16 + qcol;
        float b0 = bias[c0], b1 = bias[c1];
        float w20 = w2[c0], w21 = w2[c1];
        #pragma unroll
        for (int i = 0; i < 4; ++i) {
            #pragma unroll
            for (int reg = 0; reg < 4; ++reg) {
                int r = row0 + wr + i * 16 + qrow + reg;
                float r0 = 0.f, r1 = 0.f;
                if (resid) {
                    int bb = r / 7;   // ctx-broadcast term (h_i split)
                    r0 = resid[(size_t)bb * 1024 + c0];
                    r1 = resid[(size_t)bb * 1024 + c1];
                }
                float v = gelu_f(acc[i][0][reg] + b0 + r0) * w20
                        + gelu_f(acc[i][1][reg] + b1 + r1) * w21;
                #pragma unroll
                for (int off = 8; off > 0; off >>= 1)
                    v += __shfl_down(v, off, 16);
                if (qcol == 0)
                    atomicAdd(&rowacc[wr + i * 16 + qrow + reg], v);
            }
        }
        __syncthreads();
        if (tid < 128) atomicAdd(&ildst[row0 + tid], rowacc[tid]);
        return;
    }

    #pragma unroll
    for (int i = 0; i < 4; ++i) {
        int rbase = row0 + wr + i * 16 + qrow;
        #pragma unroll
        for (int j = 0; j < 2; ++j) {
            int c = col0 + wc + j * 16 + qcol;
            float bv = bias ? bias[c] : 0.0f;
            int seg = c >> 10, c0 = c & 1023;
            #pragma unroll
            for (int reg = 0; reg < 4; ++reg) {
                int r = rbase + reg;
                float vv = acc[i][j][reg] + bv;
                if (act) vv = gelu_f(vv);
                if (resid) vv += resid[(size_t)r * 1024 + c];
                if (Cf) Cf[(size_t)r * 1024 + c] = vv;
                if (Cb) Cb[(size_t)seg * segStride + (size_t)r * 1024 + c0] = f2b(vv);
            }
        }
    }
}

// ---------------------------------------------------------------------------
// 64x128-tile bf16 MFMA GEMM (small GEMMs: cc and ctxb).
// ---------------------------------------------------------------------------
__global__ __launch_bounds__(256) void gemm64x128(
    const unsigned short* __restrict__ A1, int a1Mode,
    const unsigned short* __restrict__ A2, int a2Mode,
    const unsigned short* __restrict__ WT, int ldw,
    const float* __restrict__ bias,
    const float* __restrict__ resid,
    float* __restrict__ Cf,
    unsigned short* __restrict__ Cb,
    int K, int act)
{
    __shared__ short As[64 * 32];
    __shared__ short Bs[128 * 32];
    const int tid = threadIdx.x;
    const int lane = tid & 63;
    const int w = tid >> 6;
    const int wc = w * 32;
    const int row0 = blockIdx.y * 64;
    const int col0 = blockIdx.x * 128;
    const int fr = lane & 15;
    const int fko = (((lane >> 4) ^ ((fr >> 1) & 3)) << 3);

    f32x4 acc[4][2] = {};

    for (int k0 = 0; k0 < K; k0 += 32) {
        const unsigned short* srcA; int mode; int kbase;
        if (k0 < 1024) { srcA = A1; mode = a1Mode; kbase = k0; }
        else           { srcA = A2; mode = a2Mode; kbase = k0 - 1024; }
        {
            int m = tid >> 2, ch = tid & 3;
            int kc = (ch ^ ((m >> 1) & 3)) * 8;
            int rr = maprow(row0 + m, mode);
            gload_lds16(srcA + (size_t)rr * 1024 + kbase + kc, &As[tid * 8]);
        }
        #pragma unroll
        for (int rnd = 0; rnd < 2; ++rnd) {
            int c = rnd * 256 + tid;
            int n = c >> 2, ch = c & 3;
            int kc = (ch ^ ((n >> 1) & 3)) * 8;
            gload_lds16(WT + (size_t)(col0 + n) * ldw + k0 + kc, &Bs[c * 8]);
        }
        __syncthreads();
        bf16x8 af[4], bf_[2];
        #pragma unroll
        for (int i = 0; i < 4; ++i)
            af[i] = *(const bf16x8*)(&As[(i * 16 + fr) * 32 + fko]);
        #pragma unroll
        for (int j = 0; j < 2; ++j)
            bf_[j] = *(const bf16x8*)(&Bs[(wc + j * 16 + fr) * 32 + fko]);
        #pragma unroll
        for (int i = 0; i < 4; ++i)
            #pragma unroll
            for (int j = 0; j < 2; ++j)
                acc[i][j] = __builtin_amdgcn_mfma_f32_16x16x32_bf16(
                    af[i], bf_[j], acc[i][j], 0, 0, 0);
        __syncthreads();
    }

    const int qrow = (lane >> 4) * 4;
    const int qcol = lane & 15;
    #pragma unroll
    for (int i = 0; i < 4; ++i) {
        int rbase = row0 + i * 16 + qrow;
        #pragma unroll
        for (int j = 0; j < 2; ++j) {
            int c = col0 + wc + j * 16 + qcol;
            float bv = bias ? bias[c] : 0.0f;
            #pragma unroll
            for (int reg = 0; reg < 4; ++reg) {
                int r = rbase + reg;
                float vv = acc[i][j][reg] + bv;
                if (act) vv = gelu_f(vv);
                if (resid) vv += resid[(size_t)r * 1024 + c];
                if (Cf) Cf[(size_t)r * 1024 + c] = vv;
                if (Cb) Cb[(size_t)r * 1024 + c] = f2b(vv);
            }
        }
    }
}

// ---------------------------------------------------------------------------
// Merged prep (R10, kept): nodes cast ([0,7168)), weight transpose+cast
// ([7168,25600)), bias/accum/il init ([25600,25628)). accums[3] doubles as
// the completion counter for the fused finalize in imp_phys_k.
// ---------------------------------------------------------------------------
__global__ __launch_bounds__(256) void prep_all(
    const float* __restrict__ nodes, unsigned short* __restrict__ nodes_b,
    const float* __restrict__ Wq, const float* __restrict__ Wk,
    const float* __restrict__ Wv, const float* __restrict__ We1,
    const float* __restrict__ Wu1, const float* __restrict__ Wu2,
    const float* __restrict__ Wi1,
    unsigned short* __restrict__ WT_all, unsigned short* __restrict__ Wu1T,
    unsigned short* __restrict__ Wu2T, unsigned short* __restrict__ Wi1T,
    const float* __restrict__ bq, const float* __restrict__ bk,
    const float* __restrict__ bv, float* __restrict__ bias_all,
    float* __restrict__ acc, float* __restrict__ il)
{
    const int ord = blockIdx.x;
    const int tid = threadIdx.x;
    __shared__ float t[32][33];

    if (ord < 7168) {
        int i = (ord * 256 + tid) * 4;
        float4 v = *(const float4*)(nodes + i);
        ushort4 o;
        o.x = f2b(v.x); o.y = f2b(v.y); o.z = f2b(v.z); o.w = f2b(v.w);
        *(ushort4*)(nodes_b + i) = o;
        return;
    }
    if (ord < 25600) {
        int flat = ord - 7168;
        int bx = flat & 31, by = (flat >> 5) & 63, z = flat >> 11;
        const float* src; unsigned short* dst; int R;
        switch (z) {
            case 0: src = Wq;            dst = WT_all;               R = 1024; break;
            case 1: src = Wk;            dst = WT_all + 1024 * 1024; R = 1024; break;
            case 2: src = Wv;            dst = WT_all + 2048 * 1024; R = 1024; break;
            case 3: src = We1;           dst = WT_all + 3072 * 1024; R = 1024; break;
            case 4: src = We1 + 1048576; dst = WT_all + 4096 * 1024; R = 1024; break;
            case 5: src = We1 + 2097152; dst = WT_all + 5120 * 1024; R = 1024; break;
            case 6: src = Wu1;           dst = Wu1T;                 R = 2048; break;
            case 7: src = Wu2;           dst = Wu2T;                 R = 1024; break;
            default: src = Wi1;          dst = Wi1T;                 R = 2048; break;
        }
        const int rt = by * 32;
        if (rt >= R) return;
        const int ct = bx * 32;
        const int tx = tid & 31, ty = tid >> 5;
        #pragma unroll
        for (int s = 0; s < 4; ++s)
            t[ty + s * 8][tx] = src[(size_t)(rt + ty + s * 8) * 1024 + ct + tx];
        __syncthreads();
        #pragma unroll
        for (int s = 0; s < 4; ++s)
            dst[(size_t)(ct + ty + s * 8) * R + rt + tx] = f2b(t[tx][ty + s * 8]);
        return;
    }
    {
        int i = (ord - 25600) * 256 + tid;
        if (i < 4) acc[i] = 0.f;
        if (i < 7168) il[i] = 0.f;
        if (i >= 5120) return;
        int seg = i >> 10, c = i & 1023;
        float v = 0.f;
        if (seg == 0) v = bq[c];
        else if (seg == 1) v = bk[c];
        else if (seg == 2) v = bv[c];
        bias_all[i] = v;
    }
}

// ---------------------------------------------------------------------------
// One block per (b,n): edge MLP + logits + softmax + messages (bf16 in/out).
// XCD-GROUPED remap (R9, measured win): each XCD owns a contiguous b-range.
// ---------------------------------------------------------------------------
__global__ __launch_bounds__(256) void attn_msg_b(
    const unsigned short* __restrict__ q, const unsigned short* __restrict__ k,
    const unsigned short* __restrict__ v,
    const unsigned short* __restrict__ la, const unsigned short* __restrict__ rb,
    const float* __restrict__ cc,
    const float* __restrict__ We2, const float* __restrict__ be2,
    float* __restrict__ attn_out, unsigned short* __restrict__ msg)
{
    const int ord = blockIdx.x;
    const int xcd = ord & 7;
    const int idx = ord >> 3;
    const int b = xcd * 128 + idx / 7;
    const int n = idx % 7;
    const int bn = b * 7 + n;
    const int tid = threadIdx.x;
    const int lane = tid & 63, wv = tid >> 6;
    const int d0 = tid * 4;
    __shared__ float red[4][14];
    __shared__ float sm[7];

    float qv[4], lav[4], wev[4];
    {
        ushort4 q4 = *(const ushort4*)(q + (size_t)bn * 1024 + d0);
        ushort4 l4 = *(const ushort4*)(la + (size_t)bn * 1024 + d0);
        float4 c4 = *(const float4*)(cc + (size_t)b * 1024 + d0);
        float4 w4 = *(const float4*)(We2 + d0);
        qv[0] = b2f(q4.x); qv[1] = b2f(q4.y); qv[2] = b2f(q4.z); qv[3] = b2f(q4.w);
        lav[0] = b2f(l4.x) + c4.x; lav[1] = b2f(l4.y) + c4.y;
        lav[2] = b2f(l4.z) + c4.z; lav[3] = b2f(l4.w) + c4.w;
        wev[0] = w4.x; wev[1] = w4.y; wev[2] = w4.z; wev[3] = w4.w;
    }

    float s1a[7], s2a[7];
    #pragma unroll
    for (int m = 0; m < 7; ++m) {
        ushort4 k4 = *(const ushort4*)(k  + (size_t)(b * 7 + m) * 1024 + d0);
        ushort4 r4 = *(const ushort4*)(rb + (size_t)(b * 7 + m) * 1024 + d0);
        s1a[m] = qv[0] * b2f(k4.x) + qv[1] * b2f(k4.y)
               + qv[2] * b2f(k4.z) + qv[3] * b2f(k4.w);
        s2a[m] = gelu_f(lav[0] + b2f(r4.x)) * wev[0]
               + gelu_f(lav[1] + b2f(r4.y)) * wev[1]
               + gelu_f(lav[2] + b2f(r4.z)) * wev[2]
               + gelu_f(lav[3] + b2f(r4.w)) * wev[3];
    }
    #pragma unroll
    for (int m = 0; m < 7; ++m) {
        float x1 = s1a[m], x2 = s2a[m];
        #pragma unroll
        for (int off = 32; off > 0; off >>= 1) {
            x1 += __shfl_down(x1, off);
            x2 += __shfl_down(x2, off);
        }
        if (lane == 0) { red[wv][m] = x1; red[wv][7 + m] = x2; }
    }
    __syncthreads();
    if (tid == 0) {
        float l[7];
        #pragma unroll
        for (int m = 0; m < 7; ++m) {
            float d1 = red[0][m] + red[1][m] + red[2][m] + red[3][m];
            float d2 = red[0][7 + m] + red[1][7 + m] + red[2][7 + m] + red[3][7 + m];
            l[m] = d1 * (1.0f / 32.0f) + d2 + be2[0]
                 + (c_adj[n * 7 + m] - 1.0f) * 10000.0f;
        }
        float mx = l[0];
        #pragma unroll
        for (int m = 1; m < 7; ++m) mx = fmaxf(mx, l[m]);
        float e[7], s = 0.f;
        #pragma unroll
        for (int m = 0; m < 7; ++m) { e[m] = __expf(l[m] - mx); s += e[m]; }
        float inv = 1.0f / s;
        #pragma unroll
        for (int m = 0; m < 7; ++m) {
            float wgt = e[m] * inv;
            sm[m] = wgt;
            attn_out[(size_t)bn * 7 + m] = wgt;
        }
    }
    __syncthreads();
    float wr_[7];
    #pragma unroll
    for (int m = 0; m < 7; ++m) wr_[m] = sm[m];
    float s0 = 0.f, s1 = 0.f, s2 = 0.f, s3 = 0.f;
    #pragma unroll
    for (int m = 0; m < 7; ++m) {
        ushort4 v4 = *(const ushort4*)(v + (size_t)(b * 7 + m) * 1024 + d0);
        s0 += wr_[m] * b2f(v4.x); s1 += wr_[m] * b2f(v4.y);
        s2 += wr_[m] * b2f(v4.z); s3 += wr_[m] * b2f(v4.w);
    }
    ushort4 o;
    o.x = f2b(s0); o.y = f2b(s1); o.z = f2b(s2); o.w = f2b(s3);
    *(ushort4*)(msg + (size_t)bn * 1024 + d0) = o;
}

// ---------------------------------------------------------------------------
// Fused tail: per-b softmax/cap/imp + fused = sum_n imp*upd + physics,
// PLUS fused finalize: last completed block (device-scope counter in
// accums[3]) computes phys/align. Counter zeroed by prep_all each run.
// ---------------------------------------------------------------------------
__global__ __launch_bounds__(256) void imp_phys_k(
    const float* __restrict__ logits, const float* __restrict__ upd,
    float* __restrict__ imp_out, float* __restrict__ fused_out,
    float* __restrict__ accums,
    float* __restrict__ phys_o, float* __restrict__ align_o)
{
    const int b = blockIdx.x;
    const int tid = threadIdx.x;
    const int lane = tid & 63, wv = tid >> 6;
    __shared__ float u[7][1024];
    __shared__ float f[1024];
    __shared__ float wsh[7];
    __shared__ float wred[4][36];

    for (int idx = tid; idx < 7 * 1024; idx += 256)
        u[idx >> 10][idx & 1023] = upd[(size_t)b * 7168 + idx];

    if (tid == 0) {
        float l[7], e[7];
        float mx = -1e30f;
        for (int i = 0; i < 7; ++i) { l[i] = logits[b * 7 + i]; mx = fmaxf(mx, l[i]); }
        float s = 0.f;
        for (int i = 0; i < 7; ++i) { e[i] = expf(l[i] - mx); s += e[i]; }
        float inv = 1.0f / s;
        float imp[7];
        for (int i = 0; i < 7; ++i) imp[i] = e[i] * inv;
        const float cap[7] = {1.f, 1.f, 1.f, 0.26f, 1.f, 1.f, 0.24f};
        const float fr[7]  = {1.f, 1.f, 1.f, 0.f,   1.f, 1.f, 0.f};
        float capped[7], capsum = 0.f, fmass = 0.f;
        for (int i = 0; i < 7; ++i) {
            capped[i] = fminf(imp[i], cap[i]);
            capsum += capped[i];
            fmass += imp[i] * fr[i];
        }
        float residual = fmaxf(1.0f - capsum, 0.0f);
        float redis[7], rs = 0.f;
        for (int i = 0; i < 7; ++i) {
            float fs = (fmass > 1e-6f) ? imp[i] * fr[i] / fmaxf(fmass, 1e-6f)
                                       : fr[i] * 0.2f;
            redis[i] = capped[i] + fs * residual;
            rs += redis[i];
        }
        float invr = 1.0f / fmaxf(rs, 1e-6f);
        for (int i = 0; i < 7; ++i) {
            float wi = redis[i] * invr;
            wsh[i] = wi;
            imp_out[b * 7 + i] = wi;
        }
    }
    __syncthreads();

    float wr[7];
    #pragma unroll
    for (int i = 0; i < 7; ++i) wr[i] = wsh[i];
    #pragma unroll
    for (int j = 0; j < 4; ++j) {
        int d = tid + j * 256;
        float s = 0.f;
        #pragma unroll
        for (int nn2 = 0; nn2 < 7; ++nn2)
            s += wr[nn2] * u[nn2][d];
        f[d] = s;
        fused_out[(size_t)b * 1024 + d] = s;
    }
    __syncthreads();

    float vals[36];
    #pragma unroll
    for (int i = 0; i < 36; ++i) vals[i] = 0.f;
    for (int d = tid; d < 1024; d += 256) {
        float x[7];
        #pragma unroll
        for (int n = 0; n < 7; ++n) x[n] = u[n][d];
        float fv = f[d];
        int idx = 0;
        #pragma unroll
        for (int n = 0; n < 7; ++n) {
            #pragma unroll
            for (int m = n; m < 7; ++m) vals[idx++] += x[n] * x[m];
        }
        #pragma unroll
        for (int n = 0; n < 7; ++n) vals[28 + n] += x[n] * fv;
        vals[35] += fv * fv;
    }
    #pragma unroll
    for (int i = 0; i < 36; ++i) {
        float s = vals[i];
        #pragma unroll
        for (int off = 32; off > 0; off >>= 1) s += __shfl_down(s, off);
        if (lane == 0) wred[wv][i] = s;
    }
    __syncthreads();
    if (tid == 0) {
        float tv[36];
        for (int i = 0; i < 36; ++i)
            tv[i] = wred[0][i] + wred[1][i] + wred[2][i] + wred[3][i];
        auto didx = [](int n, int m) -> int {
            if (n > m) { int t = n; n = m; m = t; }
            return n * 7 - n * (n - 1) / 2 + (m - n);
        };
        float norms[7];
        for (int n = 0; n < 7; ++n) norms[n] = sqrtf(tv[didx(n, n)]);
        float e = 0.f, nl = 0.f;
        for (int n = 0; n < 7; ++n)
            for (int m = 0; m < 7; ++m) {
                float cos_ = tv[didx(n, m)] / fmaxf(norms[n] * norms[m], 1e-8f);
                float adj = c_adj[n * 7 + m];
                e += (1.0f - cos_) * adj;
                if (adj == 0.0f && n != m) nl += fmaxf(cos_ - 0.35f, 0.0f);
            }
        float fnorm = sqrtf(tv[35]);
        float al = 0.f;
        for (int n = 0; n < 7; ++n) {
            float cosn = tv[28 + n] /
                         (fmaxf(norms[n], 1e-12f) * fmaxf(fnorm, 1e-12f));
            al += 1.0f - cosn;
        }
        atomicAdd(&accums[0], e);
        atomicAdd(&accums[1], nl);
        atomicAdd(&accums[2], al);

        // fused finalize: last block to finish computes the scalars
        __threadfence();
        unsigned int old = atomicAdd((unsigned int*)&accums[3], 1u);
        if (old == 1023u) {
            float a0 = atomicAdd(&accums[0], 0.0f);
            float a1 = atomicAdd(&accums[1], 0.0f);
            float a2 = atomicAdd(&accums[2], 0.0f);
            phys_o[0]  = a0 / 41.0f + 0.5f * (a1 / 8.0f);
            align_o[0] = a2 * (1.0f / 7168.0f);
        }
    }
}

extern "C" void kernel_launch(void* const* d_in, const int* in_sizes, int n_in,
                              void* d_out, int out_size, void* d_ws, size_t ws_size,
                              hipStream_t stream)
{
    const float* nodes = (const float*)d_in[0];
    const float* Wq  = (const float*)d_in[1];
    const float* bq  = (const float*)d_in[2];
    const float* Wk  = (const float*)d_in[3];
    const float* bk  = (const float*)d_in[4];
    const float* Wv  = (const float*)d_in[5];
    const float* bv  = (const float*)d_in[6];
    const float* We1 = (const float*)d_in[7];
    const float* be1 = (const float*)d_in[8];
    const float* We2 = (const float*)d_in[9];
    const float* be2 = (const float*)d_in[10];
    const float* Wu1 = (const float*)d_in[11];
    const float* bu1 = (const float*)d_in[12];
    const float* Wu2 = (const float*)d_in[13];
    const float* bu2 = (const float*)d_in[14];
    const float* Wi1 = (const float*)d_in[15];
    const float* bi1 = (const float*)d_in[16];
    const float* Wi2 = (const float*)d_in[17];
    const float* bi2 = (const float*)d_in[18];
    (void)bi2;   // constant shift of all imp logits: softmax-invariant

    float* out = (float*)d_out;
    float* fused_o = out;                            // 1,048,576
    float* upd_o   = out + 1048576;                  // 7,340,032
    float* imp_o   = out + 1048576 + 7340032;        // 7,168
    float* attn_o  = imp_o + 7168;                   // 50,176
    float* phys_o  = attn_o + 50176;                 // 1
    float* align_o = phys_o + 1;                     // 1

    const size_t BIG = 7340032;   // B*N*D
    const size_t MEG = 1048576;   // D*D
    char* p = (char*)d_ws;
    unsigned short* nodes_b = (unsigned short*)p; p += BIG * 2;
    unsigned short* qb      = (unsigned short*)p; p += BIG * 2;   // seg 0; reused: h_u
    unsigned short* kb      = (unsigned short*)p; p += BIG * 2;   // seg 1; reused: upd_b
    unsigned short* vb      = (unsigned short*)p; p += BIG * 2;   // seg 2
    unsigned short* lab     = (unsigned short*)p; p += BIG * 2;   // seg 3; reused: msg
    unsigned short* rbb     = (unsigned short*)p; p += BIG * 2;   // seg 4; reused: ctxW
    unsigned short* WT_all  = (unsigned short*)p; p += (size_t)6144 * 1024 * 2;
    unsigned short* Wu1T    = (unsigned short*)p; p += 2 * MEG * 2;
    unsigned short* Wu2T    = (unsigned short*)p; p += MEG * 2;
    unsigned short* Wi1T    = (unsigned short*)p; p += 2 * MEG * 2;
    float* bias_all = (float*)p; p += 5120 * 4;
    float* ccf = (float*)p; p += MEG * 4;
    float* il  = (float*)p; p += 7168 * 4;
    float* acc = (float*)p; p += 4 * 4;
    unsigned short* msgb = lab;   // alias: safe (see attn_msg_b)
    unsigned short* hub  = qb;
    unsigned short* updb = kb;
    float* ctxW = (float*)rbb;    // alias: rbb dead after attn_msg_b; 4MB fits

    dim3 blk(256);
    dim3 blk512(512);

    // merged prep: nodes cast + weight transposes + bias/accum/il init
    prep_all<<<dim3(25628), blk, 0, stream>>>(
        nodes, nodes_b, Wq, Wk, Wv, We1, Wu1, Wu2, Wi1,
        WT_all, Wu1T, Wu2T, Wi1T, bq, bk, bv, bias_all, acc, il);

    // fused q|k|v|la|rb : N=5120, segmented bf16 out into qb..rbb
    gemm128db<<<dim3(40, 56), blk, 0, stream>>>(
        nodes_b, 0, nullptr, 0, WT_all, 1024, bias_all, nullptr,
        nullptr, qb, BIG, 1024, 0);

    // cc = nodes[:,-1] @ Wc + be1 (fp32 out), WcT at WT_all row 5120
    gemm64x128<<<dim3(8, 16), blk, 0, stream>>>(
        nodes_b, 1, nullptr, 0, WT_all + (size_t)5120 * 1024, 1024, be1, nullptr,
        ccf, nullptr, 1024, 0);

    // attention + messages (msg overwrites la), XCD-grouped remap
    attn_msg_b<<<dim3(7168), blk, 0, stream>>>(qb, kb, vb, lab, rbb, ccf, We2, be2,
                                               attn_o, msgb);

    // h_u = gelu([nodes|msg] @ Wu1 + bu1)
    gemm128x8w<<<dim3(8, 56), blk512, 0, stream>>>(
        nodes_b, 0, msgb, 0, Wu1T, 2048, bu1, nullptr, nullptr, hub, 0, 2048, 1,
        nullptr, nullptr);
    // updated = h_u @ Wu2 + bu2 + nodes (fp32 out + bf16 copy)
    gemm128x8w<<<dim3(8, 56), blk512, 0, stream>>>(
        hub, 0, nullptr, 0, Wu2T, 1024, bu2, nodes, upd_o, updb, 0, 1024, 0,
        nullptr, nullptr);

    // ctxW[b] = updated[b,6] @ Wi1b   (h_i split: shared across the 7 nodes)
    // Wi1b^T lives at k-offset 1024 within Wi1T rows (ldw=2048).
    gemm64x128<<<dim3(8, 16), blk, 0, stream>>>(
        updb, 1, nullptr, 0, Wi1T + 1024, 2048, nullptr, nullptr,
        ctxW, nullptr, 1024, 0);

    // imp logits, K=1024 (was 2048): il[row] = sum_c gelu(
    //   (updated @ Wi1a)[row,c] + ctxW[row/7,c] + bi1[c]) * Wi2[c]
    gemm128x8w<<<dim3(8, 56), blk512, 0, stream>>>(
        updb, 0, nullptr, 0, Wi1T, 2048, bi1, ctxW, nullptr, nullptr, 0, 1024, 1,
        Wi2, il);

    // tail (finalize fused via completion counter in acc[3])
    imp_phys_k<<<dim3(1024), blk, 0, stream>>>(il, upd_o, imp_o, fused_o, acc,
                                               phys_o, align_o);
}

// Round 13
// 529.847 us; speedup vs baseline: 1.0333x; 1.0333x over previous
//
#include <hip/hip_runtime.h>
#include <hip/hip_bf16.h>

// PhysicsGraphFusion: B=1024, N=7, D=1024
// Outputs (flat): fused (B*D), updated (B*N*D), imp (B*N), attn (B*N*N), phys (1), align (1)

typedef __attribute__((ext_vector_type(8))) short bf16x8;
typedef __attribute__((ext_vector_type(4))) float f32x4;

__constant__ float c_adj[49] = {
    1,1,0,0,1,1,1,
    1,1,1,1,1,1,1,
    0,1,1,0,1,0,1,
    0,1,0,1,1,1,1,
    1,1,1,1,1,1,1,
    1,1,0,1,1,1,1,
    1,1,1,1,1,1,1};

// gelu via Abramowitz-Stegun 7.1.26 erf (|err| < 1.5e-7, ~12 VALU ops).
__device__ __forceinline__ float gelu_f(float x) {
    float z = fabsf(x) * 0.70710678118654752f;
    float t = 1.0f / (1.0f + 0.3275911f * z);
    float poly = ((((1.061405429f * t - 1.453152027f) * t + 1.421413741f) * t
                  - 0.284496736f) * t + 0.254829592f) * t;
    float e = __expf(-z * z);
    float erf_abs = 1.0f - poly * e;
    float erf = copysignf(erf_abs, x);
    return 0.5f * x * (1.0f + erf);
}
__device__ __forceinline__ float b2f(unsigned short u) {
    unsigned int x = ((unsigned int)u) << 16;
    union { unsigned int i; float f; } c; c.i = x; return c.f;
}
__device__ __forceinline__ unsigned short f2b(float f) {
    __hip_bfloat16 h = __float2bfloat16(f);
    union { __hip_bfloat16 b; unsigned short u; } c; c.b = h; return c.u;
}

__device__ __forceinline__ void gload_lds16(const void* g, void* l) {
    __builtin_amdgcn_global_load_lds(
        (const __attribute__((address_space(1))) unsigned int*)g,
        (__attribute__((address_space(3))) unsigned int*)l, 16, 0, 0);
}

// row mapping: 0: r->r ; 1: r->r*7+6 (ctx rows) ; 2: r->r-r%7+6 (ctx broadcast)
__device__ __forceinline__ int maprow(int r, int mode) {
    if (mode == 1) return r * 7 + 6;
    if (mode == 2) return r - r % 7 + 6;
    return r;
}

// ---------------------------------------------------------------------------
// 128x128-tile double-buffered 4-wave bf16 MFMA GEMM (16x16x32 frags).
// PROVEN: 118.5-122.3 us on QKV shape across R3/R7/R9/R11/R12 (15 profiled
// reps, +-0.5us), 0 bank conflicts, VGPR 76 -> ~31% occupancy.
// (R10 lesson: dual epilogues cost an occupancy step; keep single-path.)
// ---------------------------------------------------------------------------
__global__ __launch_bounds__(256) void gemm128db(
    const unsigned short* __restrict__ A1, int a1Mode,
    const unsigned short* __restrict__ A2, int a2Mode,
    const unsigned short* __restrict__ WT, int ldw,
    const float* __restrict__ bias,
    const float* __restrict__ resid,
    float* __restrict__ Cf,
    unsigned short* __restrict__ Cb, size_t segStride,
    int K, int act)
{
    __shared__ short As[2][128 * 32];
    __shared__ short Bs[2][128 * 32];
    const int tid = threadIdx.x;
    const int lane = tid & 63;
    const int w = tid >> 6;
    const int wr = (w >> 1) * 64;
    const int wc = (w & 1) * 64;

    int lin = blockIdx.y * gridDim.x + blockIdx.x;
    const int nwg = gridDim.x * gridDim.y;
    const int cpx = nwg >> 3;
    lin = (lin & 7) * cpx + (lin >> 3);
    const int row0 = (lin / gridDim.x) * 128;
    const int col0 = (lin % gridDim.x) * 128;

    const int fr = lane & 15;
    const int fko = (((lane >> 4) ^ ((fr >> 1) & 3)) << 3);

    const int NTt = K >> 5;

    auto stage = [&](int ktn) {
        int k0n = ktn * 32;
        const unsigned short* srcA; int mode; int kbase;
        if (k0n < 1024) { srcA = A1; mode = a1Mode; kbase = k0n; }
        else            { srcA = A2; mode = a2Mode; kbase = k0n - 1024; }
        short* Adst = &As[ktn & 1][0];
        short* Bdst = &Bs[ktn & 1][0];
        #pragma unroll
        for (int rnd = 0; rnd < 2; ++rnd) {
            int c = rnd * 256 + tid;
            int m = c >> 2, ch = c & 3;
            int kc = (ch ^ ((m >> 1) & 3)) * 8;
            int rr = maprow(row0 + m, mode);
            gload_lds16(srcA + (size_t)rr * 1024 + kbase + kc, Adst + c * 8);
        }
        #pragma unroll
        for (int rnd = 0; rnd < 2; ++rnd) {
            int c = rnd * 256 + tid;
            int n = c >> 2, ch = c & 3;
            int kc = (ch ^ ((n >> 1) & 3)) * 8;
            gload_lds16(WT + (size_t)(col0 + n) * ldw + k0n + kc, Bdst + c * 8);
        }
    };

    f32x4 acc[4][4] = {};

    stage(0);
    asm volatile("s_waitcnt vmcnt(0)" ::: "memory");
    asm volatile("s_barrier" ::: "memory");

    for (int kt = 0; kt < NTt; ++kt) {
        const short* Ab = &As[kt & 1][0];
        const short* Bb = &Bs[kt & 1][0];

        if (kt + 1 < NTt) stage(kt + 1);

        bf16x8 af[4], bfv[4];
        #pragma unroll
        for (int i = 0; i < 4; ++i)
            af[i] = *(const bf16x8*)(Ab + (wr + i * 16 + fr) * 32 + fko);
        #pragma unroll
        for (int j = 0; j < 4; ++j)
            bfv[j] = *(const bf16x8*)(Bb + (wc + j * 16 + fr) * 32 + fko);

        __builtin_amdgcn_s_setprio(1);
        #pragma unroll
        for (int i = 0; i < 4; ++i)
            #pragma unroll
            for (int j = 0; j < 4; ++j)
                acc[i][j] = __builtin_amdgcn_mfma_f32_16x16x32_bf16(
                    af[i], bfv[j], acc[i][j], 0, 0, 0);
        __builtin_amdgcn_s_setprio(0);

        asm volatile("s_waitcnt vmcnt(0)" ::: "memory");
        asm volatile("s_barrier" ::: "memory");
    }

    const int qrow = (lane >> 4) * 4;
    const int qcol = lane & 15;
    #pragma unroll
    for (int i = 0; i < 4; ++i) {
        int rbase = row0 + wr + i * 16 + qrow;
        #pragma unroll
        for (int j = 0; j < 4; ++j) {
            int c = col0 + wc + j * 16 + qcol;
            float bv = bias ? bias[c] : 0.0f;
            int seg = c >> 10, c0 = c & 1023;
            #pragma unroll
            for (int reg = 0; reg < 4; ++reg) {
                int r = rbase + reg;
                float vv = acc[i][j][reg] + bv;
                if (act) vv = gelu_f(vv);
                if (resid) vv += resid[(size_t)r * 1024 + c];
                if (Cf) Cf[(size_t)r * 1024 + c] = vv;
                if (Cb) Cb[(size_t)seg * segStride + (size_t)r * 1024 + c0] = f2b(vv);
            }
        }
    }
}

// ---------------------------------------------------------------------------
// 128x128-tile, 8-wave (512-thread) bf16 MFMA GEMM, 3-slot ring, counted
// vmcnt. PROVEN in R4. Used for the MLP GEMMs (448-block grids).
// Optional fused row-dot epilogue (w2 != nullptr).
// ---------------------------------------------------------------------------
__global__ __launch_bounds__(512, 4) void gemm128x8w(
    const unsigned short* __restrict__ A1, int a1Mode,
    const unsigned short* __restrict__ A2, int a2Mode,
    const unsigned short* __restrict__ WT, int ldw,
    const float* __restrict__ bias,
    const float* __restrict__ resid,
    float* __restrict__ Cf,
    unsigned short* __restrict__ Cb, size_t segStride,
    int K, int act,
    const float* __restrict__ w2, float* __restrict__ ildst)
{
    __shared__ short As[3][128 * 32];
    __shared__ short Bs[3][128 * 32];
    const int tid = threadIdx.x;
    const int lane = tid & 63;
    const int w = tid >> 6;            // 8 waves
    const int wr = (w >> 2) * 64;      // 0,64
    const int wc = (w & 3) * 32;       // 0,32,64,96

    int lin = blockIdx.y * gridDim.x + blockIdx.x;
    const int nwg = gridDim.x * gridDim.y;
    const int cpx = nwg >> 3;
    lin = (lin & 7) * cpx + (lin >> 3);
    const int row0 = (lin / gridDim.x) * 128;
    const int col0 = (lin % gridDim.x) * 128;

    const int fr = lane & 15;
    const int fko = (((lane >> 4) ^ ((fr >> 1) & 3)) << 3);

    const int sm_ = tid >> 2, sch = tid & 3;
    const int skc = (sch ^ ((sm_ >> 1) & 3)) * 8;
    const int ldsoff = tid * 8;

    const int NTt = K >> 5;

    auto stage = [&](int ktn) {
        int k0n = ktn * 32;
        const unsigned short* srcA; int mode; int kbase;
        if (k0n < 1024) { srcA = A1; mode = a1Mode; kbase = k0n; }
        else            { srcA = A2; mode = a2Mode; kbase = k0n - 1024; }
        int slot = ktn % 3;
        int rr = maprow(row0 + sm_, mode);
        gload_lds16(srcA + (size_t)rr * 1024 + kbase + skc, &As[slot][ldsoff]);
        gload_lds16(WT + (size_t)(col0 + sm_) * ldw + k0n + skc, &Bs[slot][ldsoff]);
    };

    f32x4 acc[4][2] = {};

    stage(0);
    if (NTt > 1) stage(1);
    asm volatile("s_waitcnt vmcnt(2)" ::: "memory");
    asm volatile("s_barrier" ::: "memory");

    for (int kt = 0; kt < NTt; ++kt) {
        const short* Ab = &As[kt % 3][0];
        const short* Bb = &Bs[kt % 3][0];

        if (kt + 2 < NTt) stage(kt + 2);

        bf16x8 af[4], bfv[2];
        #pragma unroll
        for (int i = 0; i < 4; ++i)
            af[i] = *(const bf16x8*)(Ab + (wr + i * 16 + fr) * 32 + fko);
        #pragma unroll
        for (int j = 0; j < 2; ++j)
            bfv[j] = *(const bf16x8*)(Bb + (wc + j * 16 + fr) * 32 + fko);

        __builtin_amdgcn_s_setprio(1);
        #pragma unroll
        for (int i = 0; i < 4; ++i)
            #pragma unroll
            for (int j = 0; j < 2; ++j)
                acc[i][j] = __builtin_amdgcn_mfma_f32_16x16x32_bf16(
                    af[i], bfv[j], acc[i][j], 0, 0, 0);
        __builtin_amdgcn_s_setprio(0);

        if (kt < NTt - 2) asm volatile("s_waitcnt vmcnt(2)" ::: "memory");
        else              asm volatile("s_waitcnt vmcnt(0)" ::: "memory");
        asm volatile("s_barrier" ::: "memory");
    }

    const int qrow = (lane >> 4) * 4;
    const int qcol = lane & 15;

    if (w2) {
        float* rowacc = (float*)&As[0][0];   // LDS reuse; all reads sealed
        if (tid < 128) rowacc[tid] = 0.f;
        __syncthreads();
        int c0 = col0 + wc + qcol;
        int c1 = col0 + wc + 16 + qcol;
        float b0 = bias[c0], b1 = bias[c1];
        float w20 = w2[c0], w21 = w2[c1];
        #pragma unroll
        for (int i = 0; i < 4; ++i) {
            #pragma unroll
            for (int reg = 0; reg < 4; ++reg) {
                float v = gelu_f(acc[i][0][reg] + b0) * w20
                        + gelu_f(acc[i][1][reg] + b1) * w21;
                #pragma unroll
                for (int off = 8; off > 0; off >>= 1)
                    v += __shfl_down(v, off, 16);
                if (qcol == 0)
                    atomicAdd(&rowacc[wr + i * 16 + qrow + reg], v);
            }
        }
        __syncthreads();
        if (tid < 128) atomicAdd(&ildst[row0 + tid], rowacc[tid]);
        return;
    }

    #pragma unroll
    for (int i = 0; i < 4; ++i) {
        int rbase = row0 + wr + i * 16 + qrow;
        #pragma unroll
        for (int j = 0; j < 2; ++j) {
            int c = col0 + wc + j * 16 + qcol;
            float bv = bias ? bias[c] : 0.0f;
            int seg = c >> 10, c0 = c & 1023;
            #pragma unroll
            for (int reg = 0; reg < 4; ++reg) {
                int r = rbase + reg;
                float vv = acc[i][j][reg] + bv;
                if (act) vv = gelu_f(vv);
                if (resid) vv += resid[(size_t)r * 1024 + c];
                if (Cf) Cf[(size_t)r * 1024 + c] = vv;
                if (Cb) Cb[(size_t)seg * segStride + (size_t)r * 1024 + c0] = f2b(vv);
            }
        }
    }
}

// ---------------------------------------------------------------------------
// 64x128-tile bf16 MFMA GEMM (only used for the small ctx GEMM).
// ---------------------------------------------------------------------------
__global__ __launch_bounds__(256) void gemm64x128(
    const unsigned short* __restrict__ A1, int a1Mode,
    const unsigned short* __restrict__ A2, int a2Mode,
    const unsigned short* __restrict__ WT, int ldw,
    const float* __restrict__ bias,
    const float* __restrict__ resid,
    float* __restrict__ Cf,
    unsigned short* __restrict__ Cb,
    int K, int act)
{
    __shared__ short As[64 * 32];
    __shared__ short Bs[128 * 32];
    const int tid = threadIdx.x;
    const int lane = tid & 63;
    const int w = tid >> 6;
    const int wc = w * 32;
    const int row0 = blockIdx.y * 64;
    const int col0 = blockIdx.x * 128;
    const int fr = lane & 15;
    const int fko = (((lane >> 4) ^ ((fr >> 1) & 3)) << 3);

    f32x4 acc[4][2] = {};

    for (int k0 = 0; k0 < K; k0 += 32) {
        const unsigned short* srcA; int mode; int kbase;
        if (k0 < 1024) { srcA = A1; mode = a1Mode; kbase = k0; }
        else           { srcA = A2; mode = a2Mode; kbase = k0 - 1024; }
        {
            int m = tid >> 2, ch = tid & 3;
            int kc = (ch ^ ((m >> 1) & 3)) * 8;
            int rr = maprow(row0 + m, mode);
            gload_lds16(srcA + (size_t)rr * 1024 + kbase + kc, &As[tid * 8]);
        }
        #pragma unroll
        for (int rnd = 0; rnd < 2; ++rnd) {
            int c = rnd * 256 + tid;
            int n = c >> 2, ch = c & 3;
            int kc = (ch ^ ((n >> 1) & 3)) * 8;
            gload_lds16(WT + (size_t)(col0 + n) * ldw + k0 + kc, &Bs[c * 8]);
        }
        __syncthreads();
        bf16x8 af[4], bf_[2];
        #pragma unroll
        for (int i = 0; i < 4; ++i)
            af[i] = *(const bf16x8*)(&As[(i * 16 + fr) * 32 + fko]);
        #pragma unroll
        for (int j = 0; j < 2; ++j)
            bf_[j] = *(const bf16x8*)(&Bs[(wc + j * 16 + fr) * 32 + fko]);
        #pragma unroll
        for (int i = 0; i < 4; ++i)
            #pragma unroll
            for (int j = 0; j < 2; ++j)
                acc[i][j] = __builtin_amdgcn_mfma_f32_16x16x32_bf16(
                    af[i], bf_[j], acc[i][j], 0, 0, 0);
        __syncthreads();
    }

    const int qrow = (lane >> 4) * 4;
    const int qcol = lane & 15;
    #pragma unroll
    for (int i = 0; i < 4; ++i) {
        int rbase = row0 + i * 16 + qrow;
        #pragma unroll
        for (int j = 0; j < 2; ++j) {
            int c = col0 + wc + j * 16 + qcol;
            float bv = bias ? bias[c] : 0.0f;
            #pragma unroll
            for (int reg = 0; reg < 4; ++reg) {
                int r = rbase + reg;
                float vv = acc[i][j][reg] + bv;
                if (act) vv = gelu_f(vv);
                if (resid) vv += resid[(size_t)r * 1024 + c];
                if (Cf) Cf[(size_t)r * 1024 + c] = vv;
                if (Cb) Cb[(size_t)r * 1024 + c] = f2b(vv);
            }
        }
    }
}

// ---------------------------------------------------------------------------
// Merged prep (R10, kept: measured win): nodes cast ([0,7168)), weight
// transpose+cast ([7168,25600)), bias/accum/il init ([25600,25628)).
// ---------------------------------------------------------------------------
__global__ __launch_bounds__(256) void prep_all(
    const float* __restrict__ nodes, unsigned short* __restrict__ nodes_b,
    const float* __restrict__ Wq, const float* __restrict__ Wk,
    const float* __restrict__ Wv, const float* __restrict__ We1,
    const float* __restrict__ Wu1, const float* __restrict__ Wu2,
    const float* __restrict__ Wi1,
    unsigned short* __restrict__ WT_all, unsigned short* __restrict__ Wu1T,
    unsigned short* __restrict__ Wu2T, unsigned short* __restrict__ Wi1T,
    const float* __restrict__ bq, const float* __restrict__ bk,
    const float* __restrict__ bv, float* __restrict__ bias_all,
    float* __restrict__ acc, float* __restrict__ il)
{
    const int ord = blockIdx.x;
    const int tid = threadIdx.x;
    __shared__ float t[32][33];

    if (ord < 7168) {
        int i = (ord * 256 + tid) * 4;
        float4 v = *(const float4*)(nodes + i);
        ushort4 o;
        o.x = f2b(v.x); o.y = f2b(v.y); o.z = f2b(v.z); o.w = f2b(v.w);
        *(ushort4*)(nodes_b + i) = o;
        return;
    }
    if (ord < 25600) {
        int flat = ord - 7168;
        int bx = flat & 31, by = (flat >> 5) & 63, z = flat >> 11;
        const float* src; unsigned short* dst; int R;
        switch (z) {
            case 0: src = Wq;            dst = WT_all;               R = 1024; break;
            case 1: src = Wk;            dst = WT_all + 1024 * 1024; R = 1024; break;
            case 2: src = Wv;            dst = WT_all + 2048 * 1024; R = 1024; break;
            case 3: src = We1;           dst = WT_all + 3072 * 1024; R = 1024; break;
            case 4: src = We1 + 1048576; dst = WT_all + 4096 * 1024; R = 1024; break;
            case 5: src = We1 + 2097152; dst = WT_all + 5120 * 1024; R = 1024; break;
            case 6: src = Wu1;           dst = Wu1T;                 R = 2048; break;
            case 7: src = Wu2;           dst = Wu2T;                 R = 1024; break;
            default: src = Wi1;          dst = Wi1T;                 R = 2048; break;
        }
        const int rt = by * 32;
        if (rt >= R) return;
        const int ct = bx * 32;
        const int tx = tid & 31, ty = tid >> 5;
        #pragma unroll
        for (int s = 0; s < 4; ++s)
            t[ty + s * 8][tx] = src[(size_t)(rt + ty + s * 8) * 1024 + ct + tx];
        __syncthreads();
        #pragma unroll
        for (int s = 0; s < 4; ++s)
            dst[(size_t)(ct + ty + s * 8) * R + rt + tx] = f2b(t[tx][ty + s * 8]);
        return;
    }
    {
        int i = (ord - 25600) * 256 + tid;
        if (i < 4) acc[i] = 0.f;
        if (i < 7168) il[i] = 0.f;
        if (i >= 5120) return;
        int seg = i >> 10, c = i & 1023;
        float v = 0.f;
        if (seg == 0) v = bq[c];
        else if (seg == 1) v = bk[c];
        else if (seg == 2) v = bv[c];
        bias_all[i] = v;
    }
}

// ---------------------------------------------------------------------------
// One block per (b,n): edge MLP + logits + softmax + messages (bf16 in/out).
// XCD-GROUPED remap (R9, measured win): each XCD owns a contiguous b-range.
// ---------------------------------------------------------------------------
__global__ __launch_bounds__(256) void attn_msg_b(
    const unsigned short* __restrict__ q, const unsigned short* __restrict__ k,
    const unsigned short* __restrict__ v,
    const unsigned short* __restrict__ la, const unsigned short* __restrict__ rb,
    const float* __restrict__ cc,
    const float* __restrict__ We2, const float* __restrict__ be2,
    float* __restrict__ attn_out, unsigned short* __restrict__ msg)
{
    const int ord = blockIdx.x;
    const int xcd = ord & 7;
    const int idx = ord >> 3;
    const int b = xcd * 128 + idx / 7;
    const int n = idx % 7;
    const int bn = b * 7 + n;
    const int tid = threadIdx.x;
    const int lane = tid & 63, wv = tid >> 6;
    const int d0 = tid * 4;
    __shared__ float red[4][14];
    __shared__ float sm[7];

    float qv[4], lav[4], wev[4];
    {
        ushort4 q4 = *(const ushort4*)(q + (size_t)bn * 1024 + d0);
        ushort4 l4 = *(const ushort4*)(la + (size_t)bn * 1024 + d0);
        float4 c4 = *(const float4*)(cc + (size_t)b * 1024 + d0);
        float4 w4 = *(const float4*)(We2 + d0);
        qv[0] = b2f(q4.x); qv[1] = b2f(q4.y); qv[2] = b2f(q4.z); qv[3] = b2f(q4.w);
        lav[0] = b2f(l4.x) + c4.x; lav[1] = b2f(l4.y) + c4.y;
        lav[2] = b2f(l4.z) + c4.z; lav[3] = b2f(l4.w) + c4.w;
        wev[0] = w4.x; wev[1] = w4.y; wev[2] = w4.z; wev[3] = w4.w;
    }

    float s1a[7], s2a[7];
    #pragma unroll
    for (int m = 0; m < 7; ++m) {
        ushort4 k4 = *(const ushort4*)(k  + (size_t)(b * 7 + m) * 1024 + d0);
        ushort4 r4 = *(const ushort4*)(rb + (size_t)(b * 7 + m) * 1024 + d0);
        s1a[m] = qv[0] * b2f(k4.x) + qv[1] * b2f(k4.y)
               + qv[2] * b2f(k4.z) + qv[3] * b2f(k4.w);
        s2a[m] = gelu_f(lav[0] + b2f(r4.x)) * wev[0]
               + gelu_f(lav[1] + b2f(r4.y)) * wev[1]
               + gelu_f(lav[2] + b2f(r4.z)) * wev[2]
               + gelu_f(lav[3] + b2f(r4.w)) * wev[3];
    }
    #pragma unroll
    for (int m = 0; m < 7; ++m) {
        float x1 = s1a[m], x2 = s2a[m];
        #pragma unroll
        for (int off = 32; off > 0; off >>= 1) {
            x1 += __shfl_down(x1, off);
            x2 += __shfl_down(x2, off);
        }
        if (lane == 0) { red[wv][m] = x1; red[wv][7 + m] = x2; }
    }
    __syncthreads();
    if (tid == 0) {
        float l[7];
        #pragma unroll
        for (int m = 0; m < 7; ++m) {
            float d1 = red[0][m] + red[1][m] + red[2][m] + red[3][m];
            float d2 = red[0][7 + m] + red[1][7 + m] + red[2][7 + m] + red[3][7 + m];
            l[m] = d1 * (1.0f / 32.0f) + d2 + be2[0]
                 + (c_adj[n * 7 + m] - 1.0f) * 10000.0f;
        }
        float mx = l[0];
        #pragma unroll
        for (int m = 1; m < 7; ++m) mx = fmaxf(mx, l[m]);
        float e[7], s = 0.f;
        #pragma unroll
        for (int m = 0; m < 7; ++m) { e[m] = __expf(l[m] - mx); s += e[m]; }
        float inv = 1.0f / s;
        #pragma unroll
        for (int m = 0; m < 7; ++m) {
            float wgt = e[m] * inv;
            sm[m] = wgt;
            attn_out[(size_t)bn * 7 + m] = wgt;
        }
    }
    __syncthreads();
    float wr_[7];
    #pragma unroll
    for (int m = 0; m < 7; ++m) wr_[m] = sm[m];
    float s0 = 0.f, s1 = 0.f, s2 = 0.f, s3 = 0.f;
    #pragma unroll
    for (int m = 0; m < 7; ++m) {
        ushort4 v4 = *(const ushort4*)(v + (size_t)(b * 7 + m) * 1024 + d0);
        s0 += wr_[m] * b2f(v4.x); s1 += wr_[m] * b2f(v4.y);
        s2 += wr_[m] * b2f(v4.z); s3 += wr_[m] * b2f(v4.w);
    }
    ushort4 o;
    o.x = f2b(s0); o.y = f2b(s1); o.z = f2b(s2); o.w = f2b(s3);
    *(ushort4*)(msg + (size_t)bn * 1024 + d0) = o;
}

// ---------------------------------------------------------------------------
// Fused tail: per-b softmax/cap/imp + fused = sum_n imp*upd + physics.
// ---------------------------------------------------------------------------
__global__ __launch_bounds__(256) void imp_phys_k(
    const float* __restrict__ logits, const float* __restrict__ upd,
    float* __restrict__ imp_out, float* __restrict__ fused_out,
    float* __restrict__ accums)
{
    const int b = blockIdx.x;
    const int tid = threadIdx.x;
    const int lane = tid & 63, wv = tid >> 6;
    __shared__ float u[7][1024];
    __shared__ float f[1024];
    __shared__ float wsh[7];
    __shared__ float wred[4][36];

    for (int idx = tid; idx < 7 * 1024; idx += 256)
        u[idx >> 10][idx & 1023] = upd[(size_t)b * 7168 + idx];

    if (tid == 0) {
        float l[7], e[7];
        float mx = -1e30f;
        for (int i = 0; i < 7; ++i) { l[i] = logits[b * 7 + i]; mx = fmaxf(mx, l[i]); }
        float s = 0.f;
        for (int i = 0; i < 7; ++i) { e[i] = expf(l[i] - mx); s += e[i]; }
        float inv = 1.0f / s;
        float imp[7];
        for (int i = 0; i < 7; ++i) imp[i] = e[i] * inv;
        const float cap[7] = {1.f, 1.f, 1.f, 0.26f, 1.f, 1.f, 0.24f};
        const float fr[7]  = {1.f, 1.f, 1.f, 0.f,   1.f, 1.f, 0.f};
        float capped[7], capsum = 0.f, fmass = 0.f;
        for (int i = 0; i < 7; ++i) {
            capped[i] = fminf(imp[i], cap[i]);
            capsum += capped[i];
            fmass += imp[i] * fr[i];
        }
        float residual = fmaxf(1.0f - capsum, 0.0f);
        float redis[7], rs = 0.f;
        for (int i = 0; i < 7; ++i) {
            float fs = (fmass > 1e-6f) ? imp[i] * fr[i] / fmaxf(fmass, 1e-6f)
                                       : fr[i] * 0.2f;
            redis[i] = capped[i] + fs * residual;
            rs += redis[i];
        }
        float invr = 1.0f / fmaxf(rs, 1e-6f);
        for (int i = 0; i < 7; ++i) {
            float wi = redis[i] * invr;
            wsh[i] = wi;
            imp_out[b * 7 + i] = wi;
        }
    }
    __syncthreads();

    float wr[7];
    #pragma unroll
    for (int i = 0; i < 7; ++i) wr[i] = wsh[i];
    #pragma unroll
    for (int j = 0; j < 4; ++j) {
        int d = tid + j * 256;
        float s = 0.f;
        #pragma unroll
        for (int nn2 = 0; nn2 < 7; ++nn2)
            s += wr[nn2] * u[nn2][d];
        f[d] = s;
        fused_out[(size_t)b * 1024 + d] = s;
    }
    __syncthreads();

    float vals[36];
    #pragma unroll
    for (int i = 0; i < 36; ++i) vals[i] = 0.f;
    for (int d = tid; d < 1024; d += 256) {
        float x[7];
        #pragma unroll
        for (int n = 0; n < 7; ++n) x[n] = u[n][d];
        float fv = f[d];
        int idx = 0;
        #pragma unroll
        for (int n = 0; n < 7; ++n) {
            #pragma unroll
            for (int m = n; m < 7; ++m) vals[idx++] += x[n] * x[m];
        }
        #pragma unroll
        for (int n = 0; n < 7; ++n) vals[28 + n] += x[n] * fv;
        vals[35] += fv * fv;
    }
    #pragma unroll
    for (int i = 0; i < 36; ++i) {
        float s = vals[i];
        #pragma unroll
        for (int off = 32; off > 0; off >>= 1) s += __shfl_down(s, off);
        if (lane == 0) wred[wv][i] = s;
    }
    __syncthreads();
    if (tid == 0) {
        float tv[36];
        for (int i = 0; i < 36; ++i)
            tv[i] = wred[0][i] + wred[1][i] + wred[2][i] + wred[3][i];
        auto didx = [](int n, int m) -> int {
            if (n > m) { int t = n; n = m; m = t; }
            return n * 7 - n * (n - 1) / 2 + (m - n);
        };
        float norms[7];
        for (int n = 0; n < 7; ++n) norms[n] = sqrtf(tv[didx(n, n)]);
        float e = 0.f, nl = 0.f;
        for (int n = 0; n < 7; ++n)
            for (int m = 0; m < 7; ++m) {
                float cos_ = tv[didx(n, m)] / fmaxf(norms[n] * norms[m], 1e-8f);
                float adj = c_adj[n * 7 + m];
                e += (1.0f - cos_) * adj;
                if (adj == 0.0f && n != m) nl += fmaxf(cos_ - 0.35f, 0.0f);
            }
        float fnorm = sqrtf(tv[35]);
        float al = 0.f;
        for (int n = 0; n < 7; ++n) {
            float cosn = tv[28 + n] /
                         (fmaxf(norms[n], 1e-12f) * fmaxf(fnorm, 1e-12f));
            al += 1.0f - cosn;
        }
        atomicAdd(&accums[0], e);
        atomicAdd(&accums[1], nl);
        atomicAdd(&accums[2], al);
    }
}

__global__ void finalize_k(const float* __restrict__ a,
                           float* __restrict__ phys_o,
                           float* __restrict__ align_o)
{
    phys_o[0]  = a[0] / 41.0f + 0.5f * (a[1] / 8.0f);
    align_o[0] = a[2] * (1.0f / 7168.0f);
}

extern "C" void kernel_launch(void* const* d_in, const int* in_sizes, int n_in,
                              void* d_out, int out_size, void* d_ws, size_t ws_size,
                              hipStream_t stream)
{
    const float* nodes = (const float*)d_in[0];
    const float* Wq  = (const float*)d_in[1];
    const float* bq  = (const float*)d_in[2];
    const float* Wk  = (const float*)d_in[3];
    const float* bk  = (const float*)d_in[4];
    const float* Wv  = (const float*)d_in[5];
    const float* bv  = (const float*)d_in[6];
    const float* We1 = (const float*)d_in[7];
    const float* be1 = (const float*)d_in[8];
    const float* We2 = (const float*)d_in[9];
    const float* be2 = (const float*)d_in[10];
    const float* Wu1 = (const float*)d_in[11];
    const float* bu1 = (const float*)d_in[12];
    const float* Wu2 = (const float*)d_in[13];
    const float* bu2 = (const float*)d_in[14];
    const float* Wi1 = (const float*)d_in[15];
    const float* bi1 = (const float*)d_in[16];
    const float* Wi2 = (const float*)d_in[17];
    const float* bi2 = (const float*)d_in[18];
    (void)bi2;   // constant shift of all imp logits: softmax-invariant

    float* out = (float*)d_out;
    float* fused_o = out;                            // 1,048,576
    float* upd_o   = out + 1048576;                  // 7,340,032
    float* imp_o   = out + 1048576 + 7340032;        // 7,168
    float* attn_o  = imp_o + 7168;                   // 50,176
    float* phys_o  = attn_o + 50176;                 // 1
    float* align_o = phys_o + 1;                     // 1

    const size_t BIG = 7340032;   // B*N*D
    const size_t MEG = 1048576;   // D*D
    char* p = (char*)d_ws;
    unsigned short* nodes_b = (unsigned short*)p; p += BIG * 2;
    unsigned short* qb      = (unsigned short*)p; p += BIG * 2;   // seg 0; reused: h_u
    unsigned short* kb      = (unsigned short*)p; p += BIG * 2;   // seg 1; reused: upd_b
    unsigned short* vb      = (unsigned short*)p; p += BIG * 2;   // seg 2
    unsigned short* lab     = (unsigned short*)p; p += BIG * 2;   // seg 3; reused: msg
    unsigned short* rbb     = (unsigned short*)p; p += BIG * 2;   // seg 4
    unsigned short* WT_all  = (unsigned short*)p; p += (size_t)6144 * 1024 * 2;
    unsigned short* Wu1T    = (unsigned short*)p; p += 2 * MEG * 2;
    unsigned short* Wu2T    = (unsigned short*)p; p += MEG * 2;
    unsigned short* Wi1T    = (unsigned short*)p; p += 2 * MEG * 2;
    float* bias_all = (float*)p; p += 5120 * 4;
    float* ccf = (float*)p; p += MEG * 4;
    float* il  = (float*)p; p += 7168 * 4;
    float* acc = (float*)p; p += 4 * 4;
    unsigned short* msgb = lab;   // alias: safe (see attn_msg_b)
    unsigned short* hub  = qb;
    unsigned short* updb = kb;

    dim3 blk(256);
    dim3 blk512(512);

    // merged prep: nodes cast + weight transposes + bias/accum/il init
    prep_all<<<dim3(25628), blk, 0, stream>>>(
        nodes, nodes_b, Wq, Wk, Wv, We1, Wu1, Wu2, Wi1,
        WT_all, Wu1T, Wu2T, Wi1T, bq, bk, bv, bias_all, acc, il);

    // fused q|k|v|la|rb : N=5120, segmented bf16 out into qb..rbb
    gemm128db<<<dim3(40, 56), blk, 0, stream>>>(
        nodes_b, 0, nullptr, 0, WT_all, 1024, bias_all, nullptr,
        nullptr, qb, BIG, 1024, 0);

    // cc = nodes[:,-1] @ Wc + be1 (fp32 out), WcT at WT_all row 5120
    gemm64x128<<<dim3(8, 16), blk, 0, stream>>>(
        nodes_b, 1, nullptr, 0, WT_all + (size_t)5120 * 1024, 1024, be1, nullptr,
        ccf, nullptr, 1024, 0);

    // attention + messages (msg overwrites la), XCD-grouped remap
    attn_msg_b<<<dim3(7168), blk, 0, stream>>>(qb, kb, vb, lab, rbb, ccf, We2, be2,
                                               attn_o, msgb);

    // h_u = gelu([nodes|msg] @ Wu1 + bu1)
    gemm128x8w<<<dim3(8, 56), blk512, 0, stream>>>(
        nodes_b, 0, msgb, 0, Wu1T, 2048, bu1, nullptr, nullptr, hub, 0, 2048, 1,
        nullptr, nullptr);
    // updated = h_u @ Wu2 + bu2 + nodes (fp32 out + bf16 copy)
    gemm128x8w<<<dim3(8, 56), blk512, 0, stream>>>(
        hub, 0, nullptr, 0, Wu2T, 1024, bu2, nodes, upd_o, updb, 0, 1024, 0,
        nullptr, nullptr);
    // imp logits: il[row] = sum_c gelu(([updated|ctx] @ Wi1 + bi1)[row,c]) * Wi2[c]
    gemm128x8w<<<dim3(8, 56), blk512, 0, stream>>>(
        updb, 0, updb, 2, Wi1T, 2048, bi1, nullptr, nullptr, nullptr, 0, 2048, 1,
        Wi2, il);

    // tail
    imp_phys_k<<<dim3(1024), blk, 0, stream>>>(il, upd_o, imp_o, fused_o, acc);
    finalize_k<<<1, 1, 0, stream>>>(acc, phys_o, align_o);
}

// Round 14
// 504.087 us; speedup vs baseline: 1.0861x; 1.0511x over previous
//
#include <hip/hip_runtime.h>
#include <hip/hip_bf16.h>

// PhysicsGraphFusion: B=1024, N=7, D=1024
// Outputs (flat): fused (B*D), updated (B*N*D), imp (B*N), attn (B*N*N), phys (1), align (1)

typedef __attribute__((ext_vector_type(8))) short bf16x8;
typedef __attribute__((ext_vector_type(4))) float f32x4;

__constant__ float c_adj[49] = {
    1,1,0,0,1,1,1,
    1,1,1,1,1,1,1,
    0,1,1,0,1,0,1,
    0,1,0,1,1,1,1,
    1,1,1,1,1,1,1,
    1,1,0,1,1,1,1,
    1,1,1,1,1,1,1};

// gelu via Abramowitz-Stegun 7.1.26 erf (|err| < 1.5e-7, ~12 VALU ops).
__device__ __forceinline__ float gelu_f(float x) {
    float z = fabsf(x) * 0.70710678118654752f;
    float t = 1.0f / (1.0f + 0.3275911f * z);
    float poly = ((((1.061405429f * t - 1.453152027f) * t + 1.421413741f) * t
                  - 0.284496736f) * t + 0.254829592f) * t;
    float e = __expf(-z * z);
    float erf_abs = 1.0f - poly * e;
    float erf = copysignf(erf_abs, x);
    return 0.5f * x * (1.0f + erf);
}
__device__ __forceinline__ float b2f(unsigned short u) {
    unsigned int x = ((unsigned int)u) << 16;
    union { unsigned int i; float f; } c; c.i = x; return c.f;
}
__device__ __forceinline__ unsigned short f2b(float f) {
    __hip_bfloat16 h = __float2bfloat16(f);
    union { __hip_bfloat16 b; unsigned short u; } c; c.b = h; return c.u;
}

__device__ __forceinline__ void gload_lds16(const void* g, void* l) {
    __builtin_amdgcn_global_load_lds(
        (const __attribute__((address_space(1))) unsigned int*)g,
        (__attribute__((address_space(3))) unsigned int*)l, 16, 0, 0);
}

// row mapping: 0: r->r ; 1: r->r*7+6 (ctx rows) ; 2: r->r-r%7+6 (ctx broadcast)
__device__ __forceinline__ int maprow(int r, int mode) {
    if (mode == 1) return r * 7 + 6;
    if (mode == 2) return r - r % 7 + 6;
    return r;
}

// ---------------------------------------------------------------------------
// QKV + cc fused, v2. EXACTLY the proven gemm128db body (119.0us, 0 bank
// conflicts, VGPR 76); all per-job differences are wave-uniform per-BLOCK
// selects (SGPRs): A-mode, WT base, bias base, Cb base. ONE epilogue path
// (segmented bf16 store) for both jobs — cc output is bf16 now (seg=0
// degenerate), consumed by attn_msg_b as ushort4. This removes R10's dual-
// epilogue VGPR bloat (104 regs -> 20% occupancy -> +27us) while keeping
// its launch-gap win (~-20us: one launch + cc dispatch gone).
//   lin <  2240 : QKV — A mode 0, WT=WTq, bias=bias_all, out=qb segmented
//   lin >= 2240 : cc  — A mode 1 (ctx rows), WT=WcT, bias=be1, out=ccb
// K=1024 for both -> block-uniform loop. Grid 2304 (%8==0, bijective swz).
// ---------------------------------------------------------------------------
__global__ __launch_bounds__(256) void gemm_qkv2(
    const unsigned short* __restrict__ A,
    const unsigned short* __restrict__ WTq,
    const float* __restrict__ biasq,
    unsigned short* __restrict__ Cbq, size_t segStrideQ,
    const unsigned short* __restrict__ WTc,
    const float* __restrict__ biasc,
    unsigned short* __restrict__ Cbc)
{
    __shared__ short As[2][128 * 32];
    __shared__ short Bs[2][128 * 32];
    const int tid = threadIdx.x;
    const int lane = tid & 63;
    const int w = tid >> 6;
    const int wr = (w >> 1) * 64;
    const int wc = (w & 1) * 64;

    int lin = blockIdx.x;
    const int nwg = gridDim.x;            // 2304
    const int cpx = nwg >> 3;
    lin = (lin & 7) * cpx + (lin >> 3);   // bijective XCD swizzle

    const bool isQ = lin < 2240;
    int row0, col0;
    if (isQ) { row0 = (lin / 40) * 128;        col0 = (lin % 40) * 128; }
    else     { int l2 = lin - 2240;
               row0 = (l2 >> 3) * 128;         col0 = (l2 & 7) * 128; }
    const int mode = isQ ? 0 : 1;                       // SGPR
    const unsigned short* WT = isQ ? WTq : WTc;         // SGPR pair
    const float* bias = isQ ? biasq : biasc;            // SGPR pair
    unsigned short* Cb = isQ ? Cbq : Cbc;               // SGPR pair
    const size_t segStride = isQ ? segStrideQ : 0;      // seg==0 for cc

    const int fr = lane & 15;
    const int fko = (((lane >> 4) ^ ((fr >> 1) & 3)) << 3);

    const int NTt = 32;   // K = 1024 for both jobs

    auto stage = [&](int ktn) {
        int k0n = ktn * 32;
        short* Adst = &As[ktn & 1][0];
        short* Bdst = &Bs[ktn & 1][0];
        #pragma unroll
        for (int rnd = 0; rnd < 2; ++rnd) {
            int c = rnd * 256 + tid;
            int m = c >> 2, ch = c & 3;
            int kc = (ch ^ ((m >> 1) & 3)) * 8;
            int rr = maprow(row0 + m, mode);
            gload_lds16(A + (size_t)rr * 1024 + k0n + kc, Adst + c * 8);
        }
        #pragma unroll
        for (int rnd = 0; rnd < 2; ++rnd) {
            int c = rnd * 256 + tid;
            int n = c >> 2, ch = c & 3;
            int kc = (ch ^ ((n >> 1) & 3)) * 8;
            gload_lds16(WT + (size_t)(col0 + n) * 1024 + k0n + kc, Bdst + c * 8);
        }
    };

    f32x4 acc[4][4] = {};

    stage(0);
    asm volatile("s_waitcnt vmcnt(0)" ::: "memory");
    asm volatile("s_barrier" ::: "memory");

    for (int kt = 0; kt < NTt; ++kt) {
        const short* Ab = &As[kt & 1][0];
        const short* Bb = &Bs[kt & 1][0];

        if (kt + 1 < NTt) stage(kt + 1);

        bf16x8 af[4], bfv[4];
        #pragma unroll
        for (int i = 0; i < 4; ++i)
            af[i] = *(const bf16x8*)(Ab + (wr + i * 16 + fr) * 32 + fko);
        #pragma unroll
        for (int j = 0; j < 4; ++j)
            bfv[j] = *(const bf16x8*)(Bb + (wc + j * 16 + fr) * 32 + fko);

        __builtin_amdgcn_s_setprio(1);
        #pragma unroll
        for (int i = 0; i < 4; ++i)
            #pragma unroll
            for (int j = 0; j < 4; ++j)
                acc[i][j] = __builtin_amdgcn_mfma_f32_16x16x32_bf16(
                    af[i], bfv[j], acc[i][j], 0, 0, 0);
        __builtin_amdgcn_s_setprio(0);

        asm volatile("s_waitcnt vmcnt(0)" ::: "memory");
        asm volatile("s_barrier" ::: "memory");
    }

    // single unified epilogue: segmented bf16 store (cc: seg==0 always)
    const int qrow = (lane >> 4) * 4;
    const int qcol = lane & 15;
    #pragma unroll
    for (int i = 0; i < 4; ++i) {
        int rbase = row0 + wr + i * 16 + qrow;
        #pragma unroll
        for (int j = 0; j < 4; ++j) {
            int c = col0 + wc + j * 16 + qcol;
            float bv = bias[c];
            int seg = c >> 10, c0 = c & 1023;
            #pragma unroll
            for (int reg = 0; reg < 4; ++reg) {
                int r = rbase + reg;
                Cb[(size_t)seg * segStride + (size_t)r * 1024 + c0] =
                    f2b(acc[i][j][reg] + bv);
            }
        }
    }
}

// ---------------------------------------------------------------------------
// 128x128-tile, 8-wave (512-thread) bf16 MFMA GEMM, 3-slot ring, counted
// vmcnt. PROVEN in R4. Used for the MLP GEMMs (448-block grids).
// Optional fused row-dot epilogue (w2 != nullptr).
// ---------------------------------------------------------------------------
__global__ __launch_bounds__(512, 4) void gemm128x8w(
    const unsigned short* __restrict__ A1, int a1Mode,
    const unsigned short* __restrict__ A2, int a2Mode,
    const unsigned short* __restrict__ WT, int ldw,
    const float* __restrict__ bias,
    const float* __restrict__ resid,
    float* __restrict__ Cf,
    unsigned short* __restrict__ Cb, size_t segStride,
    int K, int act,
    const float* __restrict__ w2, float* __restrict__ ildst)
{
    __shared__ short As[3][128 * 32];
    __shared__ short Bs[3][128 * 32];
    const int tid = threadIdx.x;
    const int lane = tid & 63;
    const int w = tid >> 6;            // 8 waves
    const int wr = (w >> 2) * 64;      // 0,64
    const int wc = (w & 3) * 32;       // 0,32,64,96

    int lin = blockIdx.y * gridDim.x + blockIdx.x;
    const int nwg = gridDim.x * gridDim.y;
    const int cpx = nwg >> 3;
    lin = (lin & 7) * cpx + (lin >> 3);
    const int row0 = (lin / gridDim.x) * 128;
    const int col0 = (lin % gridDim.x) * 128;

    const int fr = lane & 15;
    const int fko = (((lane >> 4) ^ ((fr >> 1) & 3)) << 3);

    const int sm_ = tid >> 2, sch = tid & 3;
    const int skc = (sch ^ ((sm_ >> 1) & 3)) * 8;
    const int ldsoff = tid * 8;

    const int NTt = K >> 5;

    auto stage = [&](int ktn) {
        int k0n = ktn * 32;
        const unsigned short* srcA; int mode; int kbase;
        if (k0n < 1024) { srcA = A1; mode = a1Mode; kbase = k0n; }
        else            { srcA = A2; mode = a2Mode; kbase = k0n - 1024; }
        int slot = ktn % 3;
        int rr = maprow(row0 + sm_, mode);
        gload_lds16(srcA + (size_t)rr * 1024 + kbase + skc, &As[slot][ldsoff]);
        gload_lds16(WT + (size_t)(col0 + sm_) * ldw + k0n + skc, &Bs[slot][ldsoff]);
    };

    f32x4 acc[4][2] = {};

    stage(0);
    if (NTt > 1) stage(1);
    asm volatile("s_waitcnt vmcnt(2)" ::: "memory");
    asm volatile("s_barrier" ::: "memory");

    for (int kt = 0; kt < NTt; ++kt) {
        const short* Ab = &As[kt % 3][0];
        const short* Bb = &Bs[kt % 3][0];

        if (kt + 2 < NTt) stage(kt + 2);

        bf16x8 af[4], bfv[2];
        #pragma unroll
        for (int i = 0; i < 4; ++i)
            af[i] = *(const bf16x8*)(Ab + (wr + i * 16 + fr) * 32 + fko);
        #pragma unroll
        for (int j = 0; j < 2; ++j)
            bfv[j] = *(const bf16x8*)(Bb + (wc + j * 16 + fr) * 32 + fko);

        __builtin_amdgcn_s_setprio(1);
        #pragma unroll
        for (int i = 0; i < 4; ++i)
            #pragma unroll
            for (int j = 0; j < 2; ++j)
                acc[i][j] = __builtin_amdgcn_mfma_f32_16x16x32_bf16(
                    af[i], bfv[j], acc[i][j], 0, 0, 0);
        __builtin_amdgcn_s_setprio(0);

        if (kt < NTt - 2) asm volatile("s_waitcnt vmcnt(2)" ::: "memory");
        else              asm volatile("s_waitcnt vmcnt(0)" ::: "memory");
        asm volatile("s_barrier" ::: "memory");
    }

    const int qrow = (lane >> 4) * 4;
    const int qcol = lane & 15;

    if (w2) {
        float* rowacc = (float*)&As[0][0];   // LDS reuse; all reads sealed
        if (tid < 128) rowacc[tid] = 0.f;
        __syncthreads();
        int c0 = col0 + wc + qcol;
        int c1 = col0 + wc + 16 + qcol;
        float b0 = bias[c0], b1 = bias[c1];
        float w20 = w2[c0], w21 = w2[c1];
        #pragma unroll
        for (int i = 0; i < 4; ++i) {
            #pragma unroll
            for (int reg = 0; reg < 4; ++reg) {
                float v = gelu_f(acc[i][0][reg] + b0) * w20
                        + gelu_f(acc[i][1][reg] + b1) * w21;
                #pragma unroll
                for (int off = 8; off > 0; off >>= 1)
                    v += __shfl_down(v, off, 16);
                if (qcol == 0)
                    atomicAdd(&rowacc[wr + i * 16 + qrow + reg], v);
            }
        }
        __syncthreads();
        if (tid < 128) atomicAdd(&ildst[row0 + tid], rowacc[tid]);
        return;
    }

    #pragma unroll
    for (int i = 0; i < 4; ++i) {
        int rbase = row0 + wr + i * 16 + qrow;
        #pragma unroll
        for (int j = 0; j < 2; ++j) {
            int c = col0 + wc + j * 16 + qcol;
            float bv = bias ? bias[c] : 0.0f;
            int seg = c >> 10, c0 = c & 1023;
            #pragma unroll
            for (int reg = 0; reg < 4; ++reg) {
                int r = rbase + reg;
                float vv = acc[i][j][reg] + bv;
                if (act) vv = gelu_f(vv);
                if (resid) vv += resid[(size_t)r * 1024 + c];
                if (Cf) Cf[(size_t)r * 1024 + c] = vv;
                if (Cb) Cb[(size_t)seg * segStride + (size_t)r * 1024 + c0] = f2b(vv);
            }
        }
    }
}

// ---------------------------------------------------------------------------
// Merged prep (R10, kept): nodes cast ([0,7168)), weight transpose+cast
// ([7168,25600)), bias/accum/il init ([25600,25628)). acc[0..3] zeroed —
// acc[3] is the completion counter for the fused finalize in imp_phys_k.
// ---------------------------------------------------------------------------
__global__ __launch_bounds__(256) void prep_all(
    const float* __restrict__ nodes, unsigned short* __restrict__ nodes_b,
    const float* __restrict__ Wq, const float* __restrict__ Wk,
    const float* __restrict__ Wv, const float* __restrict__ We1,
    const float* __restrict__ Wu1, const float* __restrict__ Wu2,
    const float* __restrict__ Wi1,
    unsigned short* __restrict__ WT_all, unsigned short* __restrict__ Wu1T,
    unsigned short* __restrict__ Wu2T, unsigned short* __restrict__ Wi1T,
    const float* __restrict__ bq, const float* __restrict__ bk,
    const float* __restrict__ bv, float* __restrict__ bias_all,
    float* __restrict__ acc, float* __restrict__ il)
{
    const int ord = blockIdx.x;
    const int tid = threadIdx.x;
    __shared__ float t[32][33];

    if (ord < 7168) {
        int i = (ord * 256 + tid) * 4;
        float4 v = *(const float4*)(nodes + i);
        ushort4 o;
        o.x = f2b(v.x); o.y = f2b(v.y); o.z = f2b(v.z); o.w = f2b(v.w);
        *(ushort4*)(nodes_b + i) = o;
        return;
    }
    if (ord < 25600) {
        int flat = ord - 7168;
        int bx = flat & 31, by = (flat >> 5) & 63, z = flat >> 11;
        const float* src; unsigned short* dst; int R;
        switch (z) {
            case 0: src = Wq;            dst = WT_all;               R = 1024; break;
            case 1: src = Wk;            dst = WT_all + 1024 * 1024; R = 1024; break;
            case 2: src = Wv;            dst = WT_all + 2048 * 1024; R = 1024; break;
            case 3: src = We1;           dst = WT_all + 3072 * 1024; R = 1024; break;
            case 4: src = We1 + 1048576; dst = WT_all + 4096 * 1024; R = 1024; break;
            case 5: src = We1 + 2097152; dst = WT_all + 5120 * 1024; R = 1024; break;
            case 6: src = Wu1;           dst = Wu1T;                 R = 2048; break;
            case 7: src = Wu2;           dst = Wu2T;                 R = 1024; break;
            default: src = Wi1;          dst = Wi1T;                 R = 2048; break;
        }
        const int rt = by * 32;
        if (rt >= R) return;
        const int ct = bx * 32;
        const int tx = tid & 31, ty = tid >> 5;
        #pragma unroll
        for (int s = 0; s < 4; ++s)
            t[ty + s * 8][tx] = src[(size_t)(rt + ty + s * 8) * 1024 + ct + tx];
        __syncthreads();
        #pragma unroll
        for (int s = 0; s < 4; ++s)
            dst[(size_t)(ct + ty + s * 8) * R + rt + tx] = f2b(t[tx][ty + s * 8]);
        return;
    }
    {
        int i = (ord - 25600) * 256 + tid;
        if (i < 4) acc[i] = 0.f;
        if (i < 7168) il[i] = 0.f;
        if (i >= 5120) return;
        int seg = i >> 10, c = i & 1023;
        float v = 0.f;
        if (seg == 0) v = bq[c];
        else if (seg == 1) v = bk[c];
        else if (seg == 2) v = bv[c];
        bias_all[i] = v;
    }
}

// ---------------------------------------------------------------------------
// One block per (b,n): edge MLP + logits + softmax + messages (bf16 in/out).
// XCD-GROUPED remap (R9, measured win). cc is now bf16 (from gemm_qkv2).
// ---------------------------------------------------------------------------
__global__ __launch_bounds__(256) void attn_msg_b(
    const unsigned short* __restrict__ q, const unsigned short* __restrict__ k,
    const unsigned short* __restrict__ v,
    const unsigned short* __restrict__ la, const unsigned short* __restrict__ rb,
    const unsigned short* __restrict__ ccb,
    const float* __restrict__ We2, const float* __restrict__ be2,
    float* __restrict__ attn_out, unsigned short* __restrict__ msg)
{
    const int ord = blockIdx.x;
    const int xcd = ord & 7;
    const int idx = ord >> 3;
    const int b = xcd * 128 + idx / 7;
    const int n = idx % 7;
    const int bn = b * 7 + n;
    const int tid = threadIdx.x;
    const int lane = tid & 63, wv = tid >> 6;
    const int d0 = tid * 4;
    __shared__ float red[4][14];
    __shared__ float sm[7];

    float qv[4], lav[4], wev[4];
    {
        ushort4 q4 = *(const ushort4*)(q + (size_t)bn * 1024 + d0);
        ushort4 l4 = *(const ushort4*)(la + (size_t)bn * 1024 + d0);
        ushort4 c4 = *(const ushort4*)(ccb + (size_t)b * 1024 + d0);
        float4 w4 = *(const float4*)(We2 + d0);
        qv[0] = b2f(q4.x); qv[1] = b2f(q4.y); qv[2] = b2f(q4.z); qv[3] = b2f(q4.w);
        lav[0] = b2f(l4.x) + b2f(c4.x); lav[1] = b2f(l4.y) + b2f(c4.y);
        lav[2] = b2f(l4.z) + b2f(c4.z); lav[3] = b2f(l4.w) + b2f(c4.w);
        wev[0] = w4.x; wev[1] = w4.y; wev[2] = w4.z; wev[3] = w4.w;
    }

    float s1a[7], s2a[7];
    #pragma unroll
    for (int m = 0; m < 7; ++m) {
        ushort4 k4 = *(const ushort4*)(k  + (size_t)(b * 7 + m) * 1024 + d0);
        ushort4 r4 = *(const ushort4*)(rb + (size_t)(b * 7 + m) * 1024 + d0);
        s1a[m] = qv[0] * b2f(k4.x) + qv[1] * b2f(k4.y)
               + qv[2] * b2f(k4.z) + qv[3] * b2f(k4.w);
        s2a[m] = gelu_f(lav[0] + b2f(r4.x)) * wev[0]
               + gelu_f(lav[1] + b2f(r4.y)) * wev[1]
               + gelu_f(lav[2] + b2f(r4.z)) * wev[2]
               + gelu_f(lav[3] + b2f(r4.w)) * wev[3];
    }
    #pragma unroll
    for (int m = 0; m < 7; ++m) {
        float x1 = s1a[m], x2 = s2a[m];
        #pragma unroll
        for (int off = 32; off > 0; off >>= 1) {
            x1 += __shfl_down(x1, off);
            x2 += __shfl_down(x2, off);
        }
        if (lane == 0) { red[wv][m] = x1; red[wv][7 + m] = x2; }
    }
    __syncthreads();
    if (tid == 0) {
        float l[7];
        #pragma unroll
        for (int m = 0; m < 7; ++m) {
            float d1 = red[0][m] + red[1][m] + red[2][m] + red[3][m];
            float d2 = red[0][7 + m] + red[1][7 + m] + red[2][7 + m] + red[3][7 + m];
            l[m] = d1 * (1.0f / 32.0f) + d2 + be2[0]
                 + (c_adj[n * 7 + m] - 1.0f) * 10000.0f;
        }
        float mx = l[0];
        #pragma unroll
        for (int m = 1; m < 7; ++m) mx = fmaxf(mx, l[m]);
        float e[7], s = 0.f;
        #pragma unroll
        for (int m = 0; m < 7; ++m) { e[m] = __expf(l[m] - mx); s += e[m]; }
        float inv = 1.0f / s;
        #pragma unroll
        for (int m = 0; m < 7; ++m) {
            float wgt = e[m] * inv;
            sm[m] = wgt;
            attn_out[(size_t)bn * 7 + m] = wgt;
        }
    }
    __syncthreads();
    float wr_[7];
    #pragma unroll
    for (int m = 0; m < 7; ++m) wr_[m] = sm[m];
    float s0 = 0.f, s1 = 0.f, s2 = 0.f, s3 = 0.f;
    #pragma unroll
    for (int m = 0; m < 7; ++m) {
        ushort4 v4 = *(const ushort4*)(v + (size_t)(b * 7 + m) * 1024 + d0);
        s0 += wr_[m] * b2f(v4.x); s1 += wr_[m] * b2f(v4.y);
        s2 += wr_[m] * b2f(v4.z); s3 += wr_[m] * b2f(v4.w);
    }
    ushort4 o;
    o.x = f2b(s0); o.y = f2b(s1); o.z = f2b(s2); o.w = f2b(s3);
    *(ushort4*)(msg + (size_t)bn * 1024 + d0) = o;
}

// ---------------------------------------------------------------------------
// Fused tail: per-b softmax/cap/imp + fused = sum_n imp*upd + physics,
// PLUS fused finalize (R12-verified): last completed block (device-scope
// counter in accums[3], zeroed by prep_all) computes phys/align.
// ---------------------------------------------------------------------------
__global__ __launch_bounds__(256) void imp_phys_k(
    const float* __restrict__ logits, const float* __restrict__ upd,
    float* __restrict__ imp_out, float* __restrict__ fused_out,
    float* __restrict__ accums,
    float* __restrict__ phys_o, float* __restrict__ align_o)
{
    const int b = blockIdx.x;
    const int tid = threadIdx.x;
    const int lane = tid & 63, wv = tid >> 6;
    __shared__ float u[7][1024];
    __shared__ float f[1024];
    __shared__ float wsh[7];
    __shared__ float wred[4][36];

    for (int idx = tid; idx < 7 * 1024; idx += 256)
        u[idx >> 10][idx & 1023] = upd[(size_t)b * 7168 + idx];

    if (tid == 0) {
        float l[7], e[7];
        float mx = -1e30f;
        for (int i = 0; i < 7; ++i) { l[i] = logits[b * 7 + i]; mx = fmaxf(mx, l[i]); }
        float s = 0.f;
        for (int i = 0; i < 7; ++i) { e[i] = expf(l[i] - mx); s += e[i]; }
        float inv = 1.0f / s;
        float imp[7];
        for (int i = 0; i < 7; ++i) imp[i] = e[i] * inv;
        const float cap[7] = {1.f, 1.f, 1.f, 0.26f, 1.f, 1.f, 0.24f};
        const float fr[7]  = {1.f, 1.f, 1.f, 0.f,   1.f, 1.f, 0.f};
        float capped[7], capsum = 0.f, fmass = 0.f;
        for (int i = 0; i < 7; ++i) {
            capped[i] = fminf(imp[i], cap[i]);
            capsum += capped[i];
            fmass += imp[i] * fr[i];
        }
        float residual = fmaxf(1.0f - capsum, 0.0f);
        float redis[7], rs = 0.f;
        for (int i = 0; i < 7; ++i) {
            float fs = (fmass > 1e-6f) ? imp[i] * fr[i] / fmaxf(fmass, 1e-6f)
                                       : fr[i] * 0.2f;
            redis[i] = capped[i] + fs * residual;
            rs += redis[i];
        }
        float invr = 1.0f / fmaxf(rs, 1e-6f);
        for (int i = 0; i < 7; ++i) {
            float wi = redis[i] * invr;
            wsh[i] = wi;
            imp_out[b * 7 + i] = wi;
        }
    }
    __syncthreads();

    float wr[7];
    #pragma unroll
    for (int i = 0; i < 7; ++i) wr[i] = wsh[i];
    #pragma unroll
    for (int j = 0; j < 4; ++j) {
        int d = tid + j * 256;
        float s = 0.f;
        #pragma unroll
        for (int nn2 = 0; nn2 < 7; ++nn2)
            s += wr[nn2] * u[nn2][d];
        f[d] = s;
        fused_out[(size_t)b * 1024 + d] = s;
    }
    __syncthreads();

    float vals[36];
    #pragma unroll
    for (int i = 0; i < 36; ++i) vals[i] = 0.f;
    for (int d = tid; d < 1024; d += 256) {
        float x[7];
        #pragma unroll
        for (int n = 0; n < 7; ++n) x[n] = u[n][d];
        float fv = f[d];
        int idx = 0;
        #pragma unroll
        for (int n = 0; n < 7; ++n) {
            #pragma unroll
            for (int m = n; m < 7; ++m) vals[idx++] += x[n] * x[m];
        }
        #pragma unroll
        for (int n = 0; n < 7; ++n) vals[28 + n] += x[n] * fv;
        vals[35] += fv * fv;
    }
    #pragma unroll
    for (int i = 0; i < 36; ++i) {
        float s = vals[i];
        #pragma unroll
        for (int off = 32; off > 0; off >>= 1) s += __shfl_down(s, off);
        if (lane == 0) wred[wv][i] = s;
    }
    __syncthreads();
    if (tid == 0) {
        float tv[36];
        for (int i = 0; i < 36; ++i)
            tv[i] = wred[0][i] + wred[1][i] + wred[2][i] + wred[3][i];
        auto didx = [](int n, int m) -> int {
            if (n > m) { int t = n; n = m; m = t; }
            return n * 7 - n * (n - 1) / 2 + (m - n);
        };
        float norms[7];
        for (int n = 0; n < 7; ++n) norms[n] = sqrtf(tv[didx(n, n)]);
        float e = 0.f, nl = 0.f;
        for (int n = 0; n < 7; ++n)
            for (int m = 0; m < 7; ++m) {
                float cos_ = tv[didx(n, m)] / fmaxf(norms[n] * norms[m], 1e-8f);
                float adj = c_adj[n * 7 + m];
                e += (1.0f - cos_) * adj;
                if (adj == 0.0f && n != m) nl += fmaxf(cos_ - 0.35f, 0.0f);
            }
        float fnorm = sqrtf(tv[35]);
        float al = 0.f;
        for (int n = 0; n < 7; ++n) {
            float cosn = tv[28 + n] /
                         (fmaxf(norms[n], 1e-12f) * fmaxf(fnorm, 1e-12f));
            al += 1.0f - cosn;
        }
        atomicAdd(&accums[0], e);
        atomicAdd(&accums[1], nl);
        atomicAdd(&accums[2], al);

        // fused finalize: last block to finish computes the scalars
        __threadfence();
        unsigned int old = atomicAdd((unsigned int*)&accums[3], 1u);
        if (old == 1023u) {
            float a0 = atomicAdd(&accums[0], 0.0f);
            float a1 = atomicAdd(&accums[1], 0.0f);
            float a2 = atomicAdd(&accums[2], 0.0f);
            phys_o[0]  = a0 / 41.0f + 0.5f * (a1 / 8.0f);
            align_o[0] = a2 * (1.0f / 7168.0f);
        }
    }
}

extern "C" void kernel_launch(void* const* d_in, const int* in_sizes, int n_in,
                              void* d_out, int out_size, void* d_ws, size_t ws_size,
                              hipStream_t stream)
{
    const float* nodes = (const float*)d_in[0];
    const float* Wq  = (const float*)d_in[1];
    const float* bq  = (const float*)d_in[2];
    const float* Wk  = (const float*)d_in[3];
    const float* bk  = (const float*)d_in[4];
    const float* Wv  = (const float*)d_in[5];
    const float* bv  = (const float*)d_in[6];
    const float* We1 = (const float*)d_in[7];
    const float* be1 = (const float*)d_in[8];
    const float* We2 = (const float*)d_in[9];
    const float* be2 = (const float*)d_in[10];
    const float* Wu1 = (const float*)d_in[11];
    const float* bu1 = (const float*)d_in[12];
    const float* Wu2 = (const float*)d_in[13];
    const float* bu2 = (const float*)d_in[14];
    const float* Wi1 = (const float*)d_in[15];
    const float* bi1 = (const float*)d_in[16];
    const float* Wi2 = (const float*)d_in[17];
    const float* bi2 = (const float*)d_in[18];
    (void)bi2;   // constant shift of all imp logits: softmax-invariant

    float* out = (float*)d_out;
    float* fused_o = out;                            // 1,048,576
    float* upd_o   = out + 1048576;                  // 7,340,032
    float* imp_o   = out + 1048576 + 7340032;        // 7,168
    float* attn_o  = imp_o + 7168;                   // 50,176
    float* phys_o  = attn_o + 50176;                 // 1
    float* align_o = phys_o + 1;                     // 1

    const size_t BIG = 7340032;   // B*N*D
    const size_t MEG = 1048576;   // D*D
    char* p = (char*)d_ws;
    unsigned short* nodes_b = (unsigned short*)p; p += BIG * 2;
    unsigned short* qb      = (unsigned short*)p; p += BIG * 2;   // seg 0; reused: h_u
    unsigned short* kb      = (unsigned short*)p; p += BIG * 2;   // seg 1; reused: upd_b
    unsigned short* vb      = (unsigned short*)p; p += BIG * 2;   // seg 2
    unsigned short* lab     = (unsigned short*)p; p += BIG * 2;   // seg 3; reused: msg
    unsigned short* rbb     = (unsigned short*)p; p += BIG * 2;   // seg 4
    unsigned short* WT_all  = (unsigned short*)p; p += (size_t)6144 * 1024 * 2;
    unsigned short* Wu1T    = (unsigned short*)p; p += 2 * MEG * 2;
    unsigned short* Wu2T    = (unsigned short*)p; p += MEG * 2;
    unsigned short* Wi1T    = (unsigned short*)p; p += 2 * MEG * 2;
    float* bias_all = (float*)p; p += 5120 * 4;
    unsigned short* ccb = (unsigned short*)p; p += MEG * 2;   // cc as bf16
    float* il  = (float*)p; p += 7168 * 4;
    float* acc = (float*)p; p += 4 * 4;
    unsigned short* msgb = lab;   // alias: safe (see attn_msg_b)
    unsigned short* hub  = qb;
    unsigned short* updb = kb;

    dim3 blk(256);
    dim3 blk512(512);

    // merged prep: nodes cast + weight transposes + bias/accum/il init
    prep_all<<<dim3(25628), blk, 0, stream>>>(
        nodes, nodes_b, Wq, Wk, Wv, We1, Wu1, Wu2, Wi1,
        WT_all, Wu1T, Wu2T, Wi1T, bq, bk, bv, bias_all, acc, il);

    // fused q|k|v|la|rb (2240 blocks) + cc (64 blocks), single epilogue path
    gemm_qkv2<<<dim3(2304), blk, 0, stream>>>(
        nodes_b, WT_all, bias_all, qb, BIG,
        WT_all + (size_t)5120 * 1024, be1, ccb);

    // attention + messages (msg overwrites la), XCD-grouped remap
    attn_msg_b<<<dim3(7168), blk, 0, stream>>>(qb, kb, vb, lab, rbb, ccb, We2, be2,
                                               attn_o, msgb);

    // h_u = gelu([nodes|msg] @ Wu1 + bu1)
    gemm128x8w<<<dim3(8, 56), blk512, 0, stream>>>(
        nodes_b, 0, msgb, 0, Wu1T, 2048, bu1, nullptr, nullptr, hub, 0, 2048, 1,
        nullptr, nullptr);
    // updated = h_u @ Wu2 + bu2 + nodes (fp32 out + bf16 copy)
    gemm128x8w<<<dim3(8, 56), blk512, 0, stream>>>(
        hub, 0, nullptr, 0, Wu2T, 1024, bu2, nodes, upd_o, updb, 0, 1024, 0,
        nullptr, nullptr);
    // imp logits: il[row] = sum_c gelu(([updated|ctx] @ Wi1 + bi1)[row,c]) * Wi2[c]
    gemm128x8w<<<dim3(8, 56), blk512, 0, stream>>>(
        updb, 0, updb, 2, Wi1T, 2048, bi1, nullptr, nullptr, nullptr, 0, 2048, 1,
        Wi2, il);

    // tail (finalize fused via completion counter in acc[3])
    imp_phys_k<<<dim3(1024), blk, 0, stream>>>(il, upd_o, imp_o, fused_o, acc,
                                               phys_o, align_o);
}